// Round 11
// baseline (366.647 us; speedup 1.0000x reference)
//
#include <hip/hip_runtime.h>
#include <hip/hip_bf16.h>

// SparseDecoder (Informer ProbSparse) for MI355X.
// B=8 L=2048 D=512 H=8 dh=64 DFF=2048 u=40.
// R4: radix-select topk. R6: attn on MFMA; ff split-K. R7-R9: conflict-free
// XOR-swizzled LDS; reg-mediated staging (gl_lds + swizzled src breaks coalescing).
// R10: k_sums fused into k_qkv; V bf16; 10 launches.
// R11: k_rowmax LDS-free -- MFMA B-frags loaded DIRECTLY from row-major K
//      (L2-resident; frag layout B[n=lr][k=qd*8+j] is contiguous 16B/lane);
//      zero per-tile barriers. k_qkv __launch_bounds__(256,6) to restore
//      6 waves/SIMD (R10's 92 VGPR dropped it to 5).

#define B_   8
#define L_   2048
#define D_   512
#define H_   8
#define DH_  64
#define DFF_ 2048
#define U_   40
#define BH_  64
#define NM_  16384   // B*L
#define NCK_ 16      // key chunks in k_attn2
#define CKS_ 128     // keys per chunk

typedef __bf16 bf16_t;
typedef __bf16 bf16x8 __attribute__((ext_vector_type(8)));
typedef float  f32x4  __attribute__((ext_vector_type(4)));

// ---------------- Kernel A: X fp32 -> bf16 ; + W transpose (merged) ----------------
__global__ void k_prep(const float* __restrict__ X, bf16_t* __restrict__ Xb,
                       const float* __restrict__ Wq, const float* __restrict__ Wk,
                       const float* __restrict__ Wv, bf16_t* __restrict__ WT) {
    __shared__ float tile[64][65];
    int t = threadIdx.x;
    if (blockIdx.x < 4096) {
        size_t g = (size_t)blockIdx.x * 256 + t;
        const float4* xp = (const float4*)&X[g * 8];
        float4 f0 = xp[0], f1 = xp[1];
        bf16x8 hv;
        hv[0]=(bf16_t)f0.x; hv[1]=(bf16_t)f0.y; hv[2]=(bf16_t)f0.z; hv[3]=(bf16_t)f0.w;
        hv[4]=(bf16_t)f1.x; hv[5]=(bf16_t)f1.y; hv[6]=(bf16_t)f1.z; hv[7]=(bf16_t)f1.w;
        *(bf16x8*)&Xb[g * 8] = hv;
        return;
    }
    int blk = blockIdx.x - 4096;     // 192 = 3 mats * 64 tiles
    int mat = blk >> 6, tl = blk & 63;
    int tr = (tl >> 3) << 6;
    int tc = (tl & 7) << 6;
    const float* W = (mat == 0) ? Wq : (mat == 1) ? Wk : Wv;
    #pragma unroll
    for (int i = 0; i < 16; ++i) {
        int e = t + i * 256, r = e >> 6, c = e & 63;
        tile[r][c] = W[(size_t)(tr + r) * 512 + tc + c];
    }
    __syncthreads();
    #pragma unroll
    for (int i = 0; i < 16; ++i) {
        int e = t + i * 256, r = e >> 6, c = e & 63;
        WT[(size_t)(mat * 512 + tc + r) * 512 + tr + c] = (bf16_t)tile[c][r];
    }
}

// ---------------- Kernel C: QKV projection GEMM + fused ksum/vsum partials --------
// Linear coalesced global loads -> XOR-swizzled ds_write -> conflict-free reads.
__global__ __launch_bounds__(256, 6) void k_qkv(const bf16_t* __restrict__ Xb,
        const bf16_t* __restrict__ WT,
        const float* __restrict__ bq, const float* __restrict__ bk, const float* __restrict__ bv,
        bf16_t* __restrict__ Qb, bf16_t* __restrict__ Kb, bf16_t* __restrict__ Vb,
        float* __restrict__ kpart, float* __restrict__ vpart) {
    __shared__ bf16_t As[128 * 64];  // slot (r,cs^(r&7)) holds chunk cs of row r
    __shared__ bf16_t Bs[128 * 64];
    int t = threadIdx.x;
    int m0 = blockIdx.y * 128;
    int n0 = blockIdx.x * 128;
    int wv = t >> 6, lane = t & 63, lr = lane & 15, qd = lane >> 4;
    int wm = (wv & 1) * 64, wn = (wv >> 1) * 64;
    f32x4 acc[4][4];
    #pragma unroll
    for (int a = 0; a < 4; ++a)
        #pragma unroll
        for (int b = 0; b < 4; ++b) acc[a][b] = (f32x4){0.f, 0.f, 0.f, 0.f};

    for (int kt = 0; kt < 8; ++kt) {
        // coalesced global -> regs (overlaps with previous iter's MFMAs)
        bf16x8 areg[4], breg[4];
        #pragma unroll
        for (int i = 0; i < 4; ++i) {
            int ch = i * 256 + t, r = ch >> 3, cs = ch & 7;
            areg[i] = *(const bf16x8*)&Xb[(size_t)(m0 + r) * 512 + kt * 64 + cs * 8];
            breg[i] = *(const bf16x8*)&WT[(size_t)(n0 + r) * 512 + kt * 64 + cs * 8];
        }
        __syncthreads();             // prev iter frag reads complete
        #pragma unroll
        for (int i = 0; i < 4; ++i) {
            int ch = i * 256 + t, r = ch >> 3, cs = ch & 7, c = cs ^ (r & 7);
            *(bf16x8*)&As[(r * 8 + c) * 8] = areg[i];
            *(bf16x8*)&Bs[(r * 8 + c) * 8] = breg[i];
        }
        __syncthreads();
        bf16x8 af[4][2], bfg[4][2];
        #pragma unroll
        for (int rf = 0; rf < 4; ++rf) {
            int row = wm + rf * 16 + lr;
            #pragma unroll
            for (int ks = 0; ks < 2; ++ks)
                af[rf][ks] = *(bf16x8*)&As[row * 64 + (((ks * 4 + qd) ^ (row & 7)) * 8)];
        }
        #pragma unroll
        for (int cf = 0; cf < 4; ++cf) {
            int row = wn + cf * 16 + lr;
            #pragma unroll
            for (int ks = 0; ks < 2; ++ks)
                bfg[cf][ks] = *(bf16x8*)&Bs[row * 64 + (((ks * 4 + qd) ^ (row & 7)) * 8)];
        }
        #pragma unroll
        for (int cf = 0; cf < 4; ++cf)
            #pragma unroll
            for (int rf = 0; rf < 4; ++rf) {
                acc[rf][cf] = __builtin_amdgcn_mfma_f32_16x16x32_bf16(af[rf][0], bfg[cf][0], acc[rf][cf], 0, 0, 0);
                acc[rf][cf] = __builtin_amdgcn_mfma_f32_16x16x32_bf16(af[rf][1], bfg[cf][1], acc[rf][cf], 0, 0, 0);
            }
    }
    int sec = n0 >> 9;               // 0=Q 1=K 2=V (128-tile never straddles)
    const float* bias = (sec == 0) ? bq : (sec == 1) ? bk : bv;
    float colsum[4] = {0.f, 0.f, 0.f, 0.f};
    #pragma unroll
    for (int rf = 0; rf < 4; ++rf) {
        #pragma unroll
        for (int r = 0; r < 4; ++r) {
            int m = m0 + wm + rf * 16 + qd * 4 + r;          // C row = quad*4+reg
            int b = m >> 11, l = m & 2047;
            #pragma unroll
            for (int cf = 0; cf < 4; ++cf) {
                int n = n0 + wn + cf * 16 + lr;              // C col = lane&15
                int nn = n & 511;
                int h = nn >> 6, d = nn & 63;
                float val = acc[rf][cf][r] + bias[nn];
                colsum[cf] += val;
                size_t oidx = ((size_t)(b * 8 + h) * L_ + l) * 64 + d;
                if (sec == 0)      Qb[oidx] = (bf16_t)val;
                else if (sec == 1) Kb[oidx] = (bf16_t)val;
                else               Vb[oidx] = (bf16_t)val;
            }
        }
    }
    if (sec != 0) {                  // fused column-sum partials (fp32, pre-round)
        float* sred = (float*)As;    // alias: 128 n x 8 groups (4 KB)
        __syncthreads();             // all frag reads long done; make alias safe
        int g = (wv & 1) * 4 + qd;
        #pragma unroll
        for (int cf = 0; cf < 4; ++cf)
            sred[(wn + cf * 16 + lr) * 8 + g] = colsum[cf];
        __syncthreads();
        if (t < 128) {
            float s = 0.f;
            #pragma unroll
            for (int gg = 0; gg < 8; ++gg) s += sred[t * 8 + gg];
            int nn = (n0 + t) & 511;
            int h = nn >> 6, d = nn & 63;
            int b = blockIdx.y >> 4, seg = blockIdx.y & 15;
            float* dst = (sec == 1) ? kpart : vpart;
            dst[(((size_t)(b * 8 + h)) * 16 + seg) * 64 + d] = s;
        }
    }
}

// ---------------- Kernel D: rowmax of Q@K^T + fused M (LDS-free, direct B-frags) ----
// grid (16, 64): 128 Q rows per block. K frags loaded straight from global
// (B-layout == row-major 16B chunks; K is L2-resident). No per-tile barriers.
__global__ __launch_bounds__(256) void k_rowmax(const bf16_t* __restrict__ Qb,
        const bf16_t* __restrict__ Kb, const float* __restrict__ kpart,
        float* __restrict__ Mv) {
    __shared__ float ksum_s[64];
    __shared__ float dot_s[128];
    int t = threadIdx.x;
    int bh = blockIdx.y;
    int row0 = blockIdx.x * 128;
    int wv = t >> 6, lane = t & 63, lr = lane & 15, qd = lane >> 4;
    size_t base = (size_t)bh * L_ * DH_;
    if (t < 64) {
        float a = 0.f;
        #pragma unroll
        for (int seg = 0; seg < 16; ++seg) a += kpart[((size_t)bh * 16 + seg) * 64 + t];
        ksum_s[t] = a;
    }
    bf16x8 af[2][2];                 // Q-frags pinned in regs (rows wv*32+rf*16+lr)
    #pragma unroll
    for (int rf = 0; rf < 2; ++rf)
        #pragma unroll
        for (int ks = 0; ks < 2; ++ks)
            af[rf][ks] = *(const bf16x8*)&Qb[base + (size_t)(row0 + wv * 32 + rf * 16 + lr) * 64 + ks * 32 + qd * 8];
    __syncthreads();                 // ksum_s ready (the only barrier)
    // fused M dot: q . ksum per A-layout row (rf*16+lr); reduce across qd lanes
    #pragma unroll
    for (int rf = 0; rf < 2; ++rf) {
        float v = 0.f;
        #pragma unroll
        for (int ks = 0; ks < 2; ++ks)
            #pragma unroll
            for (int j = 0; j < 8; ++j)
                v += (float)af[rf][ks][j] * ksum_s[ks * 32 + qd * 8 + j];
        v += __shfl_xor(v, 16);
        v += __shfl_xor(v, 32);
        if (qd == 0) dot_s[wv * 32 + rf * 16 + lr] = v;   // same-wave write/read: no barrier
    }
    float pmax[2][4];
    #pragma unroll
    for (int a = 0; a < 2; ++a)
        #pragma unroll
        for (int r = 0; r < 4; ++r) pmax[a][r] = -3.4e38f;

    // 128 key-tiles of 16; B-frag = contiguous 16B at K[tile*16+lr][qd*8 / 32+qd*8]
    const bf16_t* kp = &Kb[base + (size_t)lr * 64];
    #pragma unroll 4
    for (int ktile = 0; ktile < 128; ++ktile) {
        bf16x8 b0 = *(const bf16x8*)&kp[qd * 8];
        bf16x8 b1 = *(const bf16x8*)&kp[32 + qd * 8];
        kp += 16 * 64;
        #pragma unroll
        for (int rf = 0; rf < 2; ++rf) {
            f32x4 z = {0.f, 0.f, 0.f, 0.f};
            f32x4 c0 = __builtin_amdgcn_mfma_f32_16x16x32_bf16(af[rf][0], b0, z, 0, 0, 0);
            c0 = __builtin_amdgcn_mfma_f32_16x16x32_bf16(af[rf][1], b1, c0, 0, 0, 0);
            #pragma unroll
            for (int r = 0; r < 4; ++r)
                pmax[rf][r] = fmaxf(pmax[rf][r], c0[r]);
        }
    }
    #pragma unroll
    for (int rf = 0; rf < 2; ++rf)
        #pragma unroll
        for (int r = 0; r < 4; ++r) {
            float v = pmax[rf][r];
            v = fmaxf(v, __shfl_xor(v, 1));
            v = fmaxf(v, __shfl_xor(v, 2));
            v = fmaxf(v, __shfl_xor(v, 4));
            v = fmaxf(v, __shfl_xor(v, 8));
            if (lr == 0) {
                int row = wv * 32 + rf * 16 + qd * 4 + r;
                Mv[bh * L_ + row0 + row] = v - dot_s[row] * (1.0f / 2048.0f);
            }
        }
}

// ---------------- Kernel F: top-40 via binary-search radix select ----------------
__global__ void k_topk(const float* __restrict__ Mv, int* __restrict__ topidx) {
    int lane = threadIdx.x;          // 64 threads
    int bh = blockIdx.x;
    unsigned key[32];
    #pragma unroll
    for (int j = 0; j < 32; ++j) {
        unsigned b = __float_as_uint(Mv[bh * L_ + j * 64 + lane]);
        key[j] = (b & 0x80000000u) ? ~b : (b | 0x80000000u);   // monotone map
    }
    unsigned lo = 0u, hi = 0xFFFFFFFFu;
    while (lo < hi) {
        unsigned mid = lo + ((hi - lo) >> 1) + 1;
        int c = 0;
        #pragma unroll
        for (int j = 0; j < 32; ++j)
            c += __popcll(__ballot(key[j] >= mid));
        if (c >= U_) lo = mid; else hi = mid - 1;
    }
    unsigned K40 = lo;
    int c_gt = 0;
    #pragma unroll
    for (int j = 0; j < 32; ++j)
        c_gt += __popcll(__ballot(key[j] > K40));
    unsigned long long lmask = (1ull << lane) - 1ull;
    int base_gt = 0, base_eq = 0;
    #pragma unroll
    for (int j = 0; j < 32; ++j) {
        bool gt = key[j] > K40, eq = key[j] == K40;
        unsigned long long mg = __ballot(gt);
        unsigned long long me = __ballot(eq);
        if (gt) {
            int pos = base_gt + __popcll(mg & lmask);
            topidx[bh * U_ + pos] = j * 64 + lane;
        } else if (eq) {
            int ep = base_eq + __popcll(me & lmask);
            if (c_gt + ep < U_)
                topidx[bh * U_ + c_gt + ep] = j * 64 + lane;
        }
        base_gt += __popcll(mg);
        base_eq += __popcll(me);
    }
}

// ---------------- Kernel G: MFMA flash-chunk attention partials ----------------
__global__ __launch_bounds__(256) void k_attn2(const bf16_t* __restrict__ Qb,
        const bf16_t* __restrict__ Kb, const bf16_t* __restrict__ Vb,
        const int* __restrict__ topidx, float* __restrict__ part) {
    __shared__ bf16_t Qs[48 * 72];       // padded (stride 72): 2-way free reads
    __shared__ bf16_t Ks[128 * 64];      // XOR-swizzled; later aliased by P
    __shared__ bf16_t Vt[64 * 136];      // V^T [d][key], pad 136
    __shared__ float  wred[4][48];
    __shared__ float  frow[48];
    __shared__ int    tid_s[40];
    bf16_t* Ps = Ks;                     // P[48][136] = 13056 bf16 <= 16384 (alias)

    int t = threadIdx.x;
    int ck = blockIdx.x, bh = blockIdx.y;
    int c0 = ck * CKS_;
    size_t base = (size_t)bh * L_ * DH_;
    if (t < 40) tid_s[t] = topidx[bh * U_ + t];
    // K: coalesced global -> regs -> XOR-swizzled LDS (R8 lesson)
    bf16x8 kreg[4];
    #pragma unroll
    for (int i = 0; i < 4; ++i) {
        int s = i * 256 + t, r = s >> 3, cs = s & 7;
        kreg[i] = *(const bf16x8*)&Kb[base + (size_t)(c0 + r) * 64 + cs * 8];
    }
    #pragma unroll
    for (int i = 0; i < 4; ++i) {
        int s = i * 256 + t, r = s >> 3, cs = s & 7, c = cs ^ (r & 7);
        *(bf16x8*)&Ks[(r * 8 + c) * 8] = kreg[i];
    }
    __syncthreads();                     // tid_s ready (Q gather needs it)
    for (int e = t; e < 48 * 8; e += 256) {
        int r = e >> 3, c8 = e & 7;
        bf16x8 v;
        #pragma unroll
        for (int j = 0; j < 8; ++j) v[j] = (bf16_t)0.f;
        if (r < 40) v = *(const bf16x8*)&Qb[base + (size_t)tid_s[r] * 64 + c8 * 8];
        *(bf16x8*)&Qs[r * 72 + c8 * 8] = v;
    }
    // V^T build from bf16 V: coalesced bf16x8 reads, scalar LDS writes
    #pragma unroll
    for (int i = 0; i < 4; ++i) {
        int e = t + i * 256;             // 1024 chunks: 128 keys x 8
        int key = e >> 3, c8 = e & 7;
        bf16x8 v = *(const bf16x8*)&Vb[base + (size_t)(c0 + key) * 64 + c8 * 8];
        #pragma unroll
        for (int j = 0; j < 8; ++j)
            Vt[(c8 * 8 + j) * 136 + key] = v[j];
    }
    __syncthreads();

    int wv = t >> 6, lane = t & 63, lr = lane & 15, qd = lane >> 4;
    bf16x8 aq[3][2];
    #pragma unroll
    for (int tm = 0; tm < 3; ++tm)
        #pragma unroll
        for (int ks = 0; ks < 2; ++ks)
            aq[tm][ks] = *(bf16x8*)&Qs[(tm * 16 + lr) * 72 + ks * 32 + qd * 8];
    f32x4 S[3][2];
    #pragma unroll
    for (int nt = 0; nt < 2; ++nt) {
        int key = wv * 32 + nt * 16 + lr;
        bf16x8 bk0 = *(bf16x8*)&Ks[key * 64 + ((qd ^ (key & 7)) * 8)];
        bf16x8 bk1 = *(bf16x8*)&Ks[key * 64 + (((4 + qd) ^ (key & 7)) * 8)];
        #pragma unroll
        for (int tm = 0; tm < 3; ++tm) {
            f32x4 z = {0.f, 0.f, 0.f, 0.f};
            z = __builtin_amdgcn_mfma_f32_16x16x32_bf16(aq[tm][0], bk0, z, 0, 0, 0);
            S[tm][nt] = __builtin_amdgcn_mfma_f32_16x16x32_bf16(aq[tm][1], bk1, z, 0, 0, 0);
        }
    }
    float rm[3][4];
    #pragma unroll
    for (int tm = 0; tm < 3; ++tm)
        #pragma unroll
        for (int r = 0; r < 4; ++r) {
            float v = fmaxf(S[tm][0][r], S[tm][1][r]);
            v = fmaxf(v, __shfl_xor(v, 1));
            v = fmaxf(v, __shfl_xor(v, 2));
            v = fmaxf(v, __shfl_xor(v, 4));
            v = fmaxf(v, __shfl_xor(v, 8));
            rm[tm][r] = v;
        }
    if (lr == 0) {
        #pragma unroll
        for (int tm = 0; tm < 3; ++tm)
            #pragma unroll
            for (int r = 0; r < 4; ++r)
                wred[wv][tm * 16 + qd * 4 + r] = rm[tm][r];
    }
    __syncthreads();
    if (t < 48)
        frow[t] = fmaxf(fmaxf(wred[0][t], wred[1][t]), fmaxf(wred[2][t], wred[3][t]));
    __syncthreads();
    float rs_[3][4];
    #pragma unroll
    for (int tm = 0; tm < 3; ++tm) {
        #pragma unroll
        for (int r = 0; r < 4; ++r) {
            float fm = frow[tm * 16 + qd * 4 + r];
            float s0 = __expf((S[tm][0][r] - fm) * 0.125f);
            float s1 = __expf((S[tm][1][r] - fm) * 0.125f);
            Ps[(tm * 16 + qd * 4 + r) * 136 + wv * 32 + lr]      = (bf16_t)s0;
            Ps[(tm * 16 + qd * 4 + r) * 136 + wv * 32 + 16 + lr] = (bf16_t)s1;
            rs_[tm][r] = s0 + s1;
        }
    }
    #pragma unroll
    for (int tm = 0; tm < 3; ++tm)
        #pragma unroll
        for (int r = 0; r < 4; ++r) {
            float v = rs_[tm][r];
            v += __shfl_xor(v, 1);
            v += __shfl_xor(v, 2);
            v += __shfl_xor(v, 4);
            v += __shfl_xor(v, 8);
            rs_[tm][r] = v;
        }
    if (lr == 0) {
        #pragma unroll
        for (int tm = 0; tm < 3; ++tm)
            #pragma unroll
            for (int r = 0; r < 4; ++r)
                wred[wv][tm * 16 + qd * 4 + r] = rs_[tm][r];
    }
    __syncthreads();
    float* pb = &part[(((size_t)bh * NCK_ + ck) * 40) * 66];
    if (t < 40) {
        pb[t * 66 + 64] = frow[t] * 0.125f;   // m in scaled units
        pb[t * 66 + 65] = wred[0][t] + wred[1][t] + wred[2][t] + wred[3][t];
    }
    f32x4 O[3];
    #pragma unroll
    for (int tm = 0; tm < 3; ++tm) O[tm] = (f32x4){0.f, 0.f, 0.f, 0.f};
    #pragma unroll
    for (int kk = 0; kk < 4; ++kk) {
        bf16x8 bv = *(bf16x8*)&Vt[(wv * 16 + lr) * 136 + kk * 32 + qd * 8];
        #pragma unroll
        for (int tm = 0; tm < 3; ++tm) {
            bf16x8 ap = *(bf16x8*)&Ps[(tm * 16 + lr) * 136 + kk * 32 + qd * 8];
            O[tm] = __builtin_amdgcn_mfma_f32_16x16x32_bf16(ap, bv, O[tm], 0, 0, 0);
        }
    }
    #pragma unroll
    for (int tm = 0; tm < 3; ++tm)
        #pragma unroll
        for (int r = 0; r < 4; ++r) {
            int row = tm * 16 + qd * 4 + r;
            if (row < 40) pb[row * 66 + wv * 16 + lr] = O[tm][r];
        }
}

// ---------------- Kernel G2: combine chunk partials -> topout ----------------
__global__ void k_attnred(const float* __restrict__ part, float* __restrict__ tout) {
    int t = threadIdx.x, bh = blockIdx.x;
    int d = t & 63, rg = t >> 6;
    const float* pb0 = &part[((size_t)bh * NCK_) * 40 * 66];
    for (int ri = 0; ri < 10; ++ri) {
        int r = rg + 4 * ri;
        float M = -3.4e38f;
        #pragma unroll
        for (int c = 0; c < NCK_; ++c) M = fmaxf(M, pb0[(c * 40 + r) * 66 + 64]);
        float lsum = 0.f, osum = 0.f;
        #pragma unroll
        for (int c = 0; c < NCK_; ++c) {
            float w = __expf(pb0[(c * 40 + r) * 66 + 64] - M);
            lsum += w * pb0[(c * 40 + r) * 66 + 65];
            osum += w * pb0[(c * 40 + r) * 66 + d];
        }
        tout[((size_t)bh * U_ + r) * 64 + d] = osum / lsum;
    }
}

// ---------------- Kernel H: ctx-mean -> @Wo+bo -> LN1(2a) -> a2 ----------------
__global__ void k_ctx(const float* __restrict__ vpart, const float* __restrict__ topout,
                      const float* __restrict__ Wo, const float* __restrict__ bo,
                      const float* __restrict__ g1, const float* __restrict__ be1,
                      float* __restrict__ a2) {
    __shared__ float cm[512];
    __shared__ float rs[256], rq[256];
    int t = threadIdx.x, b = blockIdx.x;
    #pragma unroll
    for (int p = 0; p < 2; ++p) {
        int hd = t + p * 256;
        int h = hd >> 6, dd = hd & 63;
        int bh = b * 8 + h;
        float vs = 0.f;
        #pragma unroll
        for (int seg = 0; seg < 16; ++seg) vs += vpart[((size_t)bh * 16 + seg) * 64 + dd];
        float tsum = 0.f;
        for (int ii = 0; ii < U_; ++ii) tsum += topout[((size_t)bh * U_ + ii) * 64 + dd];
        cm[hd] = (0.98046875f * vs + tsum) * (1.0f / 2048.0f);   // 2008/2048
    }
    __syncthreads();
    float x[2];
    #pragma unroll
    for (int p = 0; p < 2; ++p) {
        int j = t + p * 256;
        float acc = bo[j];
        for (int c = 0; c < 128; ++c) {
            float4 cv = *(const float4*)&cm[c * 4];
            acc += cv.x * Wo[(size_t)(c * 4 + 0) * 512 + j];
            acc += cv.y * Wo[(size_t)(c * 4 + 1) * 512 + j];
            acc += cv.z * Wo[(size_t)(c * 4 + 2) * 512 + j];
            acc += cv.w * Wo[(size_t)(c * 4 + 3) * 512 + j];
        }
        x[p] = 2.0f * acc;           // a + dropout(a) = 2a in eval
    }
    rs[t] = x[0] + x[1];
    rq[t] = x[0] * x[0] + x[1] * x[1];
    __syncthreads();
    for (int str = 128; str > 0; str >>= 1) {
        if (t < str) { rs[t] += rs[t + str]; rq[t] += rq[t + str]; }
        __syncthreads();
    }
    float mean = rs[0] * (1.0f / 512.0f);
    float var  = rq[0] * (1.0f / 512.0f) - mean * mean;
    float rstd = rsqrtf(var + 1e-5f);
    #pragma unroll
    for (int p = 0; p < 2; ++p) {
        int j = t + p * 256;
        a2[b * 512 + j] = (x[p] - mean) * rstd * g1[j] + be1[j];
    }
}

// ---------------- Kernel I: ff1 partials over c-segments (grid 32x4) ----------------
__global__ void k_ff1p(const float* __restrict__ a2, const float* __restrict__ W1,
                       float* __restrict__ ffp) {
    __shared__ float Ws[64 * 132];   // 64 j x 128 c, pad 132
    __shared__ float as[8 * 128];
    int t = threadIdx.x;
    int jb = blockIdx.x, seg = blockIdx.y;
    int j0 = jb * 64, c0 = seg * 128;
    #pragma unroll
    for (int i = 0; i < 8; ++i) {
        int e = t + i * 256;         // 2048 float4
        int r = e >> 5, c4 = e & 31;
        *(float4*)&Ws[r * 132 + c4 * 4] =
            *(const float4*)&W1[(size_t)(j0 + r) * 512 + c0 + c4 * 4];
    }
    for (int e = t; e < 1024; e += 256) {
        int b = e >> 7, c = e & 127;
        as[b * 128 + c] = a2[b * 512 + c0 + c];
    }
    __syncthreads();
    int j = t & 63, bp = t >> 6;
    float acc0 = 0.f, acc1 = 0.f;
    for (int c = 0; c < 32; ++c) {
        float4 w  = *(float4*)&Ws[j * 132 + c * 4];
        float4 xa = *(float4*)&as[(bp * 2) * 128 + c * 4];
        float4 xb = *(float4*)&as[(bp * 2 + 1) * 128 + c * 4];
        acc0 += w.x * xa.x + w.y * xa.y + w.z * xa.z + w.w * xa.w;
        acc1 += w.x * xb.x + w.y * xb.y + w.z * xb.z + w.w * xb.w;
    }
    ffp[(size_t)(seg * 8 + bp * 2) * 2048 + j0 + j]     = acc0;
    ffp[(size_t)(seg * 8 + bp * 2 + 1) * 2048 + j0 + j] = acc1;
}

// ---------------- Kernel J1: ff2 partials; ff1-reduce+bias+relu fused in staging ----
__global__ void k_ff2p(const float* __restrict__ ffp, const float* __restrict__ b1v,
                       const float* __restrict__ W2, float* __restrict__ ff2p) {
    __shared__ float Ws[32 * 260];   // 32 d x 256 c, pad 260
    __shared__ float fs[8 * 256];
    int t = threadIdx.x;
    int db = blockIdx.x, seg = blockIdx.y;
    int d0 = db * 32, c0 = seg * 256;
    #pragma unroll
    for (int i = 0; i < 8; ++i) {
        int e = t + i * 256;         // 2048 float4
        int r = e >> 6, c4 = e & 63;
        *(float4*)&Ws[r * 260 + c4 * 4] =
            *(const float4*)&W2[(size_t)(d0 + r) * 2048 + c0 + c4 * 4];
    }
    for (int e = t; e < 2048; e += 256) {
        int b = e >> 8, c = e & 255;
        float s = b1v[c0 + c];
        #pragma unroll
        for (int sg = 0; sg < 4; ++sg) s += ffp[(size_t)(sg * 8 + b) * 2048 + c0 + c];
        fs[b * 256 + c] = fmaxf(s, 0.f);   // relu(ff1)
    }
    __syncthreads();
    int d = t & 31, b = t >> 5;
    float acc = 0.f;
    for (int c = 0; c < 64; ++c) {
        float4 w = *(float4*)&Ws[d * 260 + c * 4];
        float4 x = *(float4*)&fs[b * 256 + c * 4];
        acc += w.x * x.x + w.y * x.y + w.z * x.z + w.w * x.w;
    }
    ff2p[(size_t)(seg * 8 + b) * 512 + d0 + d] = acc;
}

// ---------------- Kernel J2: out = LN2(a2 + ff2); forecast = out@Wout + bout ----------
__global__ void k_final(const float* __restrict__ a2, const float* __restrict__ ff2p,
                        const float* __restrict__ b2v,
                        const float* __restrict__ g2, const float* __restrict__ be2,
                        const float* __restrict__ Wout, const float* __restrict__ bout,
                        float* __restrict__ dout) {
    __shared__ float rs[256], rq[256];
    int t = threadIdx.x, b = blockIdx.x;
    float f0 = b2v[t], f1 = b2v[t + 256];
    #pragma unroll
    for (int seg = 0; seg < 8; ++seg) {
        f0 += ff2p[(size_t)(seg * 8 + b) * 512 + t];
        f1 += ff2p[(size_t)(seg * 8 + b) * 512 + t + 256];
    }
    float x0 = a2[b * 512 + t] + f0;
    float x1 = a2[b * 512 + t + 256] + f1;
    rs[t] = x0 + x1;
    rq[t] = x0 * x0 + x1 * x1;
    __syncthreads();
    for (int str = 128; str > 0; str >>= 1) {
        if (t < str) { rs[t] += rs[t + str]; rq[t] += rq[t + str]; }
        __syncthreads();
    }
    float mean = rs[0] * (1.0f / 512.0f);
    float var  = rq[0] * (1.0f / 512.0f) - mean * mean;
    float rstd = rsqrtf(var + 1e-5f);
    float o0 = (x0 - mean) * rstd * g2[t]       + be2[t];
    float o1 = (x1 - mean) * rstd * g2[t + 256] + be2[t + 256];
    dout[8 + b * 512 + t]       = o0;
    dout[8 + b * 512 + t + 256] = o1;
    __syncthreads();
    rs[t] = o0 * Wout[t] + o1 * Wout[t + 256];
    __syncthreads();
    for (int str = 128; str > 0; str >>= 1) {
        if (t < str) rs[t] += rs[t + str];
        __syncthreads();
    }
    if (t == 0) dout[b] = rs[0] + bout[0];
}

extern "C" void kernel_launch(void* const* d_in, const int* in_sizes, int n_in,
                              void* d_out, int out_size, void* d_ws, size_t ws_size,
                              hipStream_t stream) {
    const float* X    = (const float*)d_in[0];
    const float* Wq   = (const float*)d_in[1];
    const float* bq   = (const float*)d_in[2];
    const float* Wk   = (const float*)d_in[3];
    const float* bk   = (const float*)d_in[4];
    const float* Wv   = (const float*)d_in[5];
    const float* bv   = (const float*)d_in[6];
    const float* Wo   = (const float*)d_in[7];
    const float* bo   = (const float*)d_in[8];
    const float* W1   = (const float*)d_in[9];
    const float* b1   = (const float*)d_in[10];
    const float* W2   = (const float*)d_in[11];
    const float* b2   = (const float*)d_in[12];
    const float* g1   = (const float*)d_in[13];
    const float* be1  = (const float*)d_in[14];
    const float* g2   = (const float*)d_in[15];
    const float* be2  = (const float*)d_in[16];
    const float* Wout = (const float*)d_in[17];
    const float* bout = (const float*)d_in[18];
    float* out = (float*)d_out;

    char* ws = (char*)d_ws;
    size_t off = 0;
    auto alloc = [&](size_t bytes) -> void* {
        void* p = ws + off;
        off += (bytes + 255) & ~(size_t)255;
        return p;
    };
    bf16_t* Xb   = (bf16_t*)alloc((size_t)NM_ * D_ * 2);          // 16.8 MB
    bf16_t* WT   = (bf16_t*)alloc((size_t)1536 * 512 * 2);        //  1.6 MB
    bf16_t* Qb   = (bf16_t*)alloc((size_t)BH_ * L_ * DH_ * 2);    // 16.8 MB
    bf16_t* Kb   = (bf16_t*)alloc((size_t)BH_ * L_ * DH_ * 2);    // 16.8 MB
    bf16_t* Vb   = (bf16_t*)alloc((size_t)BH_ * L_ * DH_ * 2);    // 16.8 MB
    float*  Mv   = (float*) alloc((size_t)BH_ * L_ * 4);
    float*  kpart= (float*) alloc((size_t)BH_ * 16 * 64 * 4);     // 256 KB
    float*  vpart= (float*) alloc((size_t)BH_ * 16 * 64 * 4);     // 256 KB
    int*    tidx = (int*)   alloc((size_t)BH_ * U_ * 4);
    float*  tout = (float*) alloc((size_t)BH_ * U_ * 64 * 4);
    float*  a2   = (float*) alloc(8 * 512 * 4);
    float*  ffp  = (float*) alloc((size_t)4 * 8 * 2048 * 4);      // 256 KB
    float*  ff2p = (float*) alloc((size_t)8 * 8 * 512 * 4);       // 128 KB
    // attention partials (64*16*40*66 fp32 = 10.8 MB) alias the dead Xb region
    float*  part = (float*)Xb;    // Xb is consumed by k_qkv before k_attn2 runs
    (void)ws_size; (void)in_sizes; (void)n_in; (void)out_size;

    hipLaunchKernelGGL(k_prep,    dim3(4096 + 192), dim3(256), 0, stream, X, Xb, Wq, Wk, Wv, WT);
    hipLaunchKernelGGL(k_qkv,     dim3(12, 128),    dim3(256), 0, stream, Xb, WT, bq, bk, bv, Qb, Kb, Vb, kpart, vpart);
    hipLaunchKernelGGL(k_rowmax,  dim3(16, 64),     dim3(256), 0, stream, Qb, Kb, kpart, Mv);
    hipLaunchKernelGGL(k_topk,    dim3(64),         dim3(64),  0, stream, Mv, tidx);
    hipLaunchKernelGGL(k_attn2,   dim3(NCK_, 64),   dim3(256), 0, stream, Qb, Kb, Vb, tidx, part);
    hipLaunchKernelGGL(k_attnred, dim3(64),         dim3(256), 0, stream, part, tout);
    hipLaunchKernelGGL(k_ctx,     dim3(8),          dim3(256), 0, stream, vpart, tout, Wo, bo, g1, be1, a2);
    hipLaunchKernelGGL(k_ff1p,    dim3(32, 4),      dim3(256), 0, stream, a2, W1, ffp);
    hipLaunchKernelGGL(k_ff2p,    dim3(16, 8),      dim3(256), 0, stream, ffp, b1, W2, ff2p);
    hipLaunchKernelGGL(k_final,   dim3(8),          dim3(256), 0, stream, a2, ff2p, b2, g2, be2, Wout, bout, out);
}

// Round 12
// 296.725 us; speedup vs baseline: 1.2356x; 1.2356x over previous
//
#include <hip/hip_runtime.h>
#include <hip/hip_bf16.h>

// SparseDecoder (Informer ProbSparse) for MI355X.
// B=8 L=2048 D=512 H=8 dh=64 DFF=2048 u=40.
// R4: radix-select topk. R6: attn on MFMA; ff split-K. R7-R9: conflict-free
// XOR-swizzled LDS; reg-mediated staging (gl_lds + swizzled src breaks coalescing).
// R10: k_sums fused into k_qkv; V bf16; 10 launches.
// R11 FAILED: LDS-free k_rowmax (direct global B-frags) 47->124us -- every
//   wave re-pulls full K from L2 at ~200cyc latency; LDS reuse is essential.
// R12: revert k_rowmax to R10 staging; keep __launch_bounds__(256,6) on k_qkv.

#define B_   8
#define L_   2048
#define D_   512
#define H_   8
#define DH_  64
#define DFF_ 2048
#define U_   40
#define BH_  64
#define NM_  16384   // B*L
#define NCK_ 16      // key chunks in k_attn2
#define CKS_ 128     // keys per chunk

typedef __bf16 bf16_t;
typedef __bf16 bf16x8 __attribute__((ext_vector_type(8)));
typedef float  f32x4  __attribute__((ext_vector_type(4)));

// ---------------- Kernel A: X fp32 -> bf16 ; + W transpose (merged) ----------------
__global__ void k_prep(const float* __restrict__ X, bf16_t* __restrict__ Xb,
                       const float* __restrict__ Wq, const float* __restrict__ Wk,
                       const float* __restrict__ Wv, bf16_t* __restrict__ WT) {
    __shared__ float tile[64][65];
    int t = threadIdx.x;
    if (blockIdx.x < 4096) {
        size_t g = (size_t)blockIdx.x * 256 + t;
        const float4* xp = (const float4*)&X[g * 8];
        float4 f0 = xp[0], f1 = xp[1];
        bf16x8 hv;
        hv[0]=(bf16_t)f0.x; hv[1]=(bf16_t)f0.y; hv[2]=(bf16_t)f0.z; hv[3]=(bf16_t)f0.w;
        hv[4]=(bf16_t)f1.x; hv[5]=(bf16_t)f1.y; hv[6]=(bf16_t)f1.z; hv[7]=(bf16_t)f1.w;
        *(bf16x8*)&Xb[g * 8] = hv;
        return;
    }
    int blk = blockIdx.x - 4096;     // 192 = 3 mats * 64 tiles
    int mat = blk >> 6, tl = blk & 63;
    int tr = (tl >> 3) << 6;
    int tc = (tl & 7) << 6;
    const float* W = (mat == 0) ? Wq : (mat == 1) ? Wk : Wv;
    #pragma unroll
    for (int i = 0; i < 16; ++i) {
        int e = t + i * 256, r = e >> 6, c = e & 63;
        tile[r][c] = W[(size_t)(tr + r) * 512 + tc + c];
    }
    __syncthreads();
    #pragma unroll
    for (int i = 0; i < 16; ++i) {
        int e = t + i * 256, r = e >> 6, c = e & 63;
        WT[(size_t)(mat * 512 + tc + r) * 512 + tr + c] = (bf16_t)tile[c][r];
    }
}

// ---------------- Kernel C: QKV projection GEMM + fused ksum/vsum partials --------
// Linear coalesced global loads -> XOR-swizzled ds_write -> conflict-free reads.
__global__ __launch_bounds__(256, 6) void k_qkv(const bf16_t* __restrict__ Xb,
        const bf16_t* __restrict__ WT,
        const float* __restrict__ bq, const float* __restrict__ bk, const float* __restrict__ bv,
        bf16_t* __restrict__ Qb, bf16_t* __restrict__ Kb, bf16_t* __restrict__ Vb,
        float* __restrict__ kpart, float* __restrict__ vpart) {
    __shared__ bf16_t As[128 * 64];  // slot (r,cs^(r&7)) holds chunk cs of row r
    __shared__ bf16_t Bs[128 * 64];
    int t = threadIdx.x;
    int m0 = blockIdx.y * 128;
    int n0 = blockIdx.x * 128;
    int wv = t >> 6, lane = t & 63, lr = lane & 15, qd = lane >> 4;
    int wm = (wv & 1) * 64, wn = (wv >> 1) * 64;
    f32x4 acc[4][4];
    #pragma unroll
    for (int a = 0; a < 4; ++a)
        #pragma unroll
        for (int b = 0; b < 4; ++b) acc[a][b] = (f32x4){0.f, 0.f, 0.f, 0.f};

    for (int kt = 0; kt < 8; ++kt) {
        // coalesced global -> regs (overlaps with previous iter's MFMAs)
        bf16x8 areg[4], breg[4];
        #pragma unroll
        for (int i = 0; i < 4; ++i) {
            int ch = i * 256 + t, r = ch >> 3, cs = ch & 7;
            areg[i] = *(const bf16x8*)&Xb[(size_t)(m0 + r) * 512 + kt * 64 + cs * 8];
            breg[i] = *(const bf16x8*)&WT[(size_t)(n0 + r) * 512 + kt * 64 + cs * 8];
        }
        __syncthreads();             // prev iter frag reads complete
        #pragma unroll
        for (int i = 0; i < 4; ++i) {
            int ch = i * 256 + t, r = ch >> 3, cs = ch & 7, c = cs ^ (r & 7);
            *(bf16x8*)&As[(r * 8 + c) * 8] = areg[i];
            *(bf16x8*)&Bs[(r * 8 + c) * 8] = breg[i];
        }
        __syncthreads();
        bf16x8 af[4][2], bfg[4][2];
        #pragma unroll
        for (int rf = 0; rf < 4; ++rf) {
            int row = wm + rf * 16 + lr;
            #pragma unroll
            for (int ks = 0; ks < 2; ++ks)
                af[rf][ks] = *(bf16x8*)&As[row * 64 + (((ks * 4 + qd) ^ (row & 7)) * 8)];
        }
        #pragma unroll
        for (int cf = 0; cf < 4; ++cf) {
            int row = wn + cf * 16 + lr;
            #pragma unroll
            for (int ks = 0; ks < 2; ++ks)
                bfg[cf][ks] = *(bf16x8*)&Bs[row * 64 + (((ks * 4 + qd) ^ (row & 7)) * 8)];
        }
        #pragma unroll
        for (int cf = 0; cf < 4; ++cf)
            #pragma unroll
            for (int rf = 0; rf < 4; ++rf) {
                acc[rf][cf] = __builtin_amdgcn_mfma_f32_16x16x32_bf16(af[rf][0], bfg[cf][0], acc[rf][cf], 0, 0, 0);
                acc[rf][cf] = __builtin_amdgcn_mfma_f32_16x16x32_bf16(af[rf][1], bfg[cf][1], acc[rf][cf], 0, 0, 0);
            }
    }
    int sec = n0 >> 9;               // 0=Q 1=K 2=V (128-tile never straddles)
    const float* bias = (sec == 0) ? bq : (sec == 1) ? bk : bv;
    float colsum[4] = {0.f, 0.f, 0.f, 0.f};
    #pragma unroll
    for (int rf = 0; rf < 4; ++rf) {
        #pragma unroll
        for (int r = 0; r < 4; ++r) {
            int m = m0 + wm + rf * 16 + qd * 4 + r;          // C row = quad*4+reg
            int b = m >> 11, l = m & 2047;
            #pragma unroll
            for (int cf = 0; cf < 4; ++cf) {
                int n = n0 + wn + cf * 16 + lr;              // C col = lane&15
                int nn = n & 511;
                int h = nn >> 6, d = nn & 63;
                float val = acc[rf][cf][r] + bias[nn];
                colsum[cf] += val;
                size_t oidx = ((size_t)(b * 8 + h) * L_ + l) * 64 + d;
                if (sec == 0)      Qb[oidx] = (bf16_t)val;
                else if (sec == 1) Kb[oidx] = (bf16_t)val;
                else               Vb[oidx] = (bf16_t)val;
            }
        }
    }
    if (sec != 0) {                  // fused column-sum partials (fp32, pre-round)
        float* sred = (float*)As;    // alias: 128 n x 8 groups (4 KB)
        __syncthreads();             // all frag reads long done; make alias safe
        int g = (wv & 1) * 4 + qd;
        #pragma unroll
        for (int cf = 0; cf < 4; ++cf)
            sred[(wn + cf * 16 + lr) * 8 + g] = colsum[cf];
        __syncthreads();
        if (t < 128) {
            float s = 0.f;
            #pragma unroll
            for (int gg = 0; gg < 8; ++gg) s += sred[t * 8 + gg];
            int nn = (n0 + t) & 511;
            int h = nn >> 6, d = nn & 63;
            int b = blockIdx.y >> 4, seg = blockIdx.y & 15;
            float* dst = (sec == 1) ? kpart : vpart;
            dst[(((size_t)(b * 8 + h)) * 16 + seg) * 64 + d] = s;
        }
    }
}

// ---------------- Kernel D: rowmax of Q@K^T + fused M ----------------
// grid (16, 64): 128 Q rows per block. Reg-mediated swizzled K staging.
__global__ __launch_bounds__(256) void k_rowmax(const bf16_t* __restrict__ Qb,
        const bf16_t* __restrict__ Kb, const float* __restrict__ kpart,
        float* __restrict__ Mv) {
    __shared__ bf16_t Ks[128 * 64];  // XOR-swizzled layout
    __shared__ float ksum_s[64];
    __shared__ float dot_s[128];
    int t = threadIdx.x;
    int bh = blockIdx.y;
    int row0 = blockIdx.x * 128;
    int wv = t >> 6, lane = t & 63, lr = lane & 15, qd = lane >> 4;
    size_t base = (size_t)bh * L_ * DH_;
    if (t < 64) {
        float a = 0.f;
        #pragma unroll
        for (int seg = 0; seg < 16; ++seg) a += kpart[((size_t)bh * 16 + seg) * 64 + t];
        ksum_s[t] = a;
    }
    bf16x8 af[2][2];                 // Q-frags pinned in regs (rows wv*32+rf*16+lr)
    #pragma unroll
    for (int rf = 0; rf < 2; ++rf)
        #pragma unroll
        for (int ks = 0; ks < 2; ++ks)
            af[rf][ks] = *(const bf16x8*)&Qb[base + (size_t)(row0 + wv * 32 + rf * 16 + lr) * 64 + ks * 32 + qd * 8];
    __syncthreads();                 // ksum_s ready
    // fused M dot: q . ksum per A-layout row (rf*16+lr); reduce across qd lanes
    #pragma unroll
    for (int rf = 0; rf < 2; ++rf) {
        float v = 0.f;
        #pragma unroll
        for (int ks = 0; ks < 2; ++ks)
            #pragma unroll
            for (int j = 0; j < 8; ++j)
                v += (float)af[rf][ks][j] * ksum_s[ks * 32 + qd * 8 + j];
        v += __shfl_xor(v, 16);
        v += __shfl_xor(v, 32);
        if (qd == 0) dot_s[wv * 32 + rf * 16 + lr] = v;   // same-wave write/read: no barrier
    }
    float pmax[2][4];
    #pragma unroll
    for (int a = 0; a < 2; ++a)
        #pragma unroll
        for (int r = 0; r < 4; ++r) pmax[a][r] = -3.4e38f;

    for (int cb = 0; cb < 16; ++cb) {
        bf16x8 kreg[4];              // coalesced global -> regs
        #pragma unroll
        for (int i = 0; i < 4; ++i) {
            int ch = i * 256 + t, r = ch >> 3, cs = ch & 7;
            kreg[i] = *(const bf16x8*)&Kb[base + (size_t)(cb * 128 + r) * 64 + cs * 8];
        }
        __syncthreads();
        #pragma unroll
        for (int i = 0; i < 4; ++i) {
            int ch = i * 256 + t, r = ch >> 3, cs = ch & 7, c = cs ^ (r & 7);
            *(bf16x8*)&Ks[(r * 8 + c) * 8] = kreg[i];
        }
        __syncthreads();
        #pragma unroll
        for (int cf = 0; cf < 8; cf += 2) {
            int keyA = cf * 16 + lr, keyB = (cf + 1) * 16 + lr;
            bf16x8 bA0 = *(bf16x8*)&Ks[keyA * 64 + ((qd ^ (keyA & 7)) * 8)];
            bf16x8 bA1 = *(bf16x8*)&Ks[keyA * 64 + (((4 + qd) ^ (keyA & 7)) * 8)];
            bf16x8 bB0 = *(bf16x8*)&Ks[keyB * 64 + ((qd ^ (keyB & 7)) * 8)];
            bf16x8 bB1 = *(bf16x8*)&Ks[keyB * 64 + (((4 + qd) ^ (keyB & 7)) * 8)];
            #pragma unroll
            for (int rf = 0; rf < 2; ++rf) {
                f32x4 z = {0.f, 0.f, 0.f, 0.f};
                f32x4 c0 = __builtin_amdgcn_mfma_f32_16x16x32_bf16(af[rf][0], bA0, z, 0, 0, 0);
                c0 = __builtin_amdgcn_mfma_f32_16x16x32_bf16(af[rf][1], bA1, c0, 0, 0, 0);
                f32x4 c1 = __builtin_amdgcn_mfma_f32_16x16x32_bf16(af[rf][0], bB0, z, 0, 0, 0);
                c1 = __builtin_amdgcn_mfma_f32_16x16x32_bf16(af[rf][1], bB1, c1, 0, 0, 0);
                #pragma unroll
                for (int r = 0; r < 4; ++r)
                    pmax[rf][r] = fmaxf(pmax[rf][r], fmaxf(c0[r], c1[r]));
            }
        }
    }
    #pragma unroll
    for (int rf = 0; rf < 2; ++rf)
        #pragma unroll
        for (int r = 0; r < 4; ++r) {
            float v = pmax[rf][r];
            v = fmaxf(v, __shfl_xor(v, 1));
            v = fmaxf(v, __shfl_xor(v, 2));
            v = fmaxf(v, __shfl_xor(v, 4));
            v = fmaxf(v, __shfl_xor(v, 8));
            if (lr == 0) {
                int row = wv * 32 + rf * 16 + qd * 4 + r;
                Mv[bh * L_ + row0 + row] = v - dot_s[row] * (1.0f / 2048.0f);
            }
        }
}

// ---------------- Kernel F: top-40 via binary-search radix select ----------------
__global__ void k_topk(const float* __restrict__ Mv, int* __restrict__ topidx) {
    int lane = threadIdx.x;          // 64 threads
    int bh = blockIdx.x;
    unsigned key[32];
    #pragma unroll
    for (int j = 0; j < 32; ++j) {
        unsigned b = __float_as_uint(Mv[bh * L_ + j * 64 + lane]);
        key[j] = (b & 0x80000000u) ? ~b : (b | 0x80000000u);   // monotone map
    }
    unsigned lo = 0u, hi = 0xFFFFFFFFu;
    while (lo < hi) {
        unsigned mid = lo + ((hi - lo) >> 1) + 1;
        int c = 0;
        #pragma unroll
        for (int j = 0; j < 32; ++j)
            c += __popcll(__ballot(key[j] >= mid));
        if (c >= U_) lo = mid; else hi = mid - 1;
    }
    unsigned K40 = lo;
    int c_gt = 0;
    #pragma unroll
    for (int j = 0; j < 32; ++j)
        c_gt += __popcll(__ballot(key[j] > K40));
    unsigned long long lmask = (1ull << lane) - 1ull;
    int base_gt = 0, base_eq = 0;
    #pragma unroll
    for (int j = 0; j < 32; ++j) {
        bool gt = key[j] > K40, eq = key[j] == K40;
        unsigned long long mg = __ballot(gt);
        unsigned long long me = __ballot(eq);
        if (gt) {
            int pos = base_gt + __popcll(mg & lmask);
            topidx[bh * U_ + pos] = j * 64 + lane;
        } else if (eq) {
            int ep = base_eq + __popcll(me & lmask);
            if (c_gt + ep < U_)
                topidx[bh * U_ + c_gt + ep] = j * 64 + lane;
        }
        base_gt += __popcll(mg);
        base_eq += __popcll(me);
    }
}

// ---------------- Kernel G: MFMA flash-chunk attention partials ----------------
__global__ __launch_bounds__(256) void k_attn2(const bf16_t* __restrict__ Qb,
        const bf16_t* __restrict__ Kb, const bf16_t* __restrict__ Vb,
        const int* __restrict__ topidx, float* __restrict__ part) {
    __shared__ bf16_t Qs[48 * 72];       // padded (stride 72): 2-way free reads
    __shared__ bf16_t Ks[128 * 64];      // XOR-swizzled; later aliased by P
    __shared__ bf16_t Vt[64 * 136];      // V^T [d][key], pad 136
    __shared__ float  wred[4][48];
    __shared__ float  frow[48];
    __shared__ int    tid_s[40];
    bf16_t* Ps = Ks;                     // P[48][136] = 13056 bf16 <= 16384 (alias)

    int t = threadIdx.x;
    int ck = blockIdx.x, bh = blockIdx.y;
    int c0 = ck * CKS_;
    size_t base = (size_t)bh * L_ * DH_;
    if (t < 40) tid_s[t] = topidx[bh * U_ + t];
    // K: coalesced global -> regs -> XOR-swizzled LDS (R8 lesson)
    bf16x8 kreg[4];
    #pragma unroll
    for (int i = 0; i < 4; ++i) {
        int s = i * 256 + t, r = s >> 3, cs = s & 7;
        kreg[i] = *(const bf16x8*)&Kb[base + (size_t)(c0 + r) * 64 + cs * 8];
    }
    #pragma unroll
    for (int i = 0; i < 4; ++i) {
        int s = i * 256 + t, r = s >> 3, cs = s & 7, c = cs ^ (r & 7);
        *(bf16x8*)&Ks[(r * 8 + c) * 8] = kreg[i];
    }
    __syncthreads();                     // tid_s ready (Q gather needs it)
    for (int e = t; e < 48 * 8; e += 256) {
        int r = e >> 3, c8 = e & 7;
        bf16x8 v;
        #pragma unroll
        for (int j = 0; j < 8; ++j) v[j] = (bf16_t)0.f;
        if (r < 40) v = *(const bf16x8*)&Qb[base + (size_t)tid_s[r] * 64 + c8 * 8];
        *(bf16x8*)&Qs[r * 72 + c8 * 8] = v;
    }
    // V^T build from bf16 V: coalesced bf16x8 reads, scalar LDS writes
    #pragma unroll
    for (int i = 0; i < 4; ++i) {
        int e = t + i * 256;             // 1024 chunks: 128 keys x 8
        int key = e >> 3, c8 = e & 7;
        bf16x8 v = *(const bf16x8*)&Vb[base + (size_t)(c0 + key) * 64 + c8 * 8];
        #pragma unroll
        for (int j = 0; j < 8; ++j)
            Vt[(c8 * 8 + j) * 136 + key] = v[j];
    }
    __syncthreads();

    int wv = t >> 6, lane = t & 63, lr = lane & 15, qd = lane >> 4;
    bf16x8 aq[3][2];
    #pragma unroll
    for (int tm = 0; tm < 3; ++tm)
        #pragma unroll
        for (int ks = 0; ks < 2; ++ks)
            aq[tm][ks] = *(bf16x8*)&Qs[(tm * 16 + lr) * 72 + ks * 32 + qd * 8];
    f32x4 S[3][2];
    #pragma unroll
    for (int nt = 0; nt < 2; ++nt) {
        int key = wv * 32 + nt * 16 + lr;
        bf16x8 bk0 = *(bf16x8*)&Ks[key * 64 + ((qd ^ (key & 7)) * 8)];
        bf16x8 bk1 = *(bf16x8*)&Ks[key * 64 + (((4 + qd) ^ (key & 7)) * 8)];
        #pragma unroll
        for (int tm = 0; tm < 3; ++tm) {
            f32x4 z = {0.f, 0.f, 0.f, 0.f};
            z = __builtin_amdgcn_mfma_f32_16x16x32_bf16(aq[tm][0], bk0, z, 0, 0, 0);
            S[tm][nt] = __builtin_amdgcn_mfma_f32_16x16x32_bf16(aq[tm][1], bk1, z, 0, 0, 0);
        }
    }
    float rm[3][4];
    #pragma unroll
    for (int tm = 0; tm < 3; ++tm)
        #pragma unroll
        for (int r = 0; r < 4; ++r) {
            float v = fmaxf(S[tm][0][r], S[tm][1][r]);
            v = fmaxf(v, __shfl_xor(v, 1));
            v = fmaxf(v, __shfl_xor(v, 2));
            v = fmaxf(v, __shfl_xor(v, 4));
            v = fmaxf(v, __shfl_xor(v, 8));
            rm[tm][r] = v;
        }
    if (lr == 0) {
        #pragma unroll
        for (int tm = 0; tm < 3; ++tm)
            #pragma unroll
            for (int r = 0; r < 4; ++r)
                wred[wv][tm * 16 + qd * 4 + r] = rm[tm][r];
    }
    __syncthreads();
    if (t < 48)
        frow[t] = fmaxf(fmaxf(wred[0][t], wred[1][t]), fmaxf(wred[2][t], wred[3][t]));
    __syncthreads();
    float rs_[3][4];
    #pragma unroll
    for (int tm = 0; tm < 3; ++tm) {
        #pragma unroll
        for (int r = 0; r < 4; ++r) {
            float fm = frow[tm * 16 + qd * 4 + r];
            float s0 = __expf((S[tm][0][r] - fm) * 0.125f);
            float s1 = __expf((S[tm][1][r] - fm) * 0.125f);
            Ps[(tm * 16 + qd * 4 + r) * 136 + wv * 32 + lr]      = (bf16_t)s0;
            Ps[(tm * 16 + qd * 4 + r) * 136 + wv * 32 + 16 + lr] = (bf16_t)s1;
            rs_[tm][r] = s0 + s1;
        }
    }
    #pragma unroll
    for (int tm = 0; tm < 3; ++tm)
        #pragma unroll
        for (int r = 0; r < 4; ++r) {
            float v = rs_[tm][r];
            v += __shfl_xor(v, 1);
            v += __shfl_xor(v, 2);
            v += __shfl_xor(v, 4);
            v += __shfl_xor(v, 8);
            rs_[tm][r] = v;
        }
    if (lr == 0) {
        #pragma unroll
        for (int tm = 0; tm < 3; ++tm)
            #pragma unroll
            for (int r = 0; r < 4; ++r)
                wred[wv][tm * 16 + qd * 4 + r] = rs_[tm][r];
    }
    __syncthreads();
    float* pb = &part[(((size_t)bh * NCK_ + ck) * 40) * 66];
    if (t < 40) {
        pb[t * 66 + 64] = frow[t] * 0.125f;   // m in scaled units
        pb[t * 66 + 65] = wred[0][t] + wred[1][t] + wred[2][t] + wred[3][t];
    }
    f32x4 O[3];
    #pragma unroll
    for (int tm = 0; tm < 3; ++tm) O[tm] = (f32x4){0.f, 0.f, 0.f, 0.f};
    #pragma unroll
    for (int kk = 0; kk < 4; ++kk) {
        bf16x8 bv = *(bf16x8*)&Vt[(wv * 16 + lr) * 136 + kk * 32 + qd * 8];
        #pragma unroll
        for (int tm = 0; tm < 3; ++tm) {
            bf16x8 ap = *(bf16x8*)&Ps[(tm * 16 + lr) * 136 + kk * 32 + qd * 8];
            O[tm] = __builtin_amdgcn_mfma_f32_16x16x32_bf16(ap, bv, O[tm], 0, 0, 0);
        }
    }
    #pragma unroll
    for (int tm = 0; tm < 3; ++tm)
        #pragma unroll
        for (int r = 0; r < 4; ++r) {
            int row = tm * 16 + qd * 4 + r;
            if (row < 40) pb[row * 66 + wv * 16 + lr] = O[tm][r];
        }
}

// ---------------- Kernel G2: combine chunk partials -> topout ----------------
__global__ void k_attnred(const float* __restrict__ part, float* __restrict__ tout) {
    int t = threadIdx.x, bh = blockIdx.x;
    int d = t & 63, rg = t >> 6;
    const float* pb0 = &part[((size_t)bh * NCK_) * 40 * 66];
    for (int ri = 0; ri < 10; ++ri) {
        int r = rg + 4 * ri;
        float M = -3.4e38f;
        #pragma unroll
        for (int c = 0; c < NCK_; ++c) M = fmaxf(M, pb0[(c * 40 + r) * 66 + 64]);
        float lsum = 0.f, osum = 0.f;
        #pragma unroll
        for (int c = 0; c < NCK_; ++c) {
            float w = __expf(pb0[(c * 40 + r) * 66 + 64] - M);
            lsum += w * pb0[(c * 40 + r) * 66 + 65];
            osum += w * pb0[(c * 40 + r) * 66 + d];
        }
        tout[((size_t)bh * U_ + r) * 64 + d] = osum / lsum;
    }
}

// ---------------- Kernel H: ctx-mean -> @Wo+bo -> LN1(2a) -> a2 ----------------
__global__ void k_ctx(const float* __restrict__ vpart, const float* __restrict__ topout,
                      const float* __restrict__ Wo, const float* __restrict__ bo,
                      const float* __restrict__ g1, const float* __restrict__ be1,
                      float* __restrict__ a2) {
    __shared__ float cm[512];
    __shared__ float rs[256], rq[256];
    int t = threadIdx.x, b = blockIdx.x;
    #pragma unroll
    for (int p = 0; p < 2; ++p) {
        int hd = t + p * 256;
        int h = hd >> 6, dd = hd & 63;
        int bh = b * 8 + h;
        float vs = 0.f;
        #pragma unroll
        for (int seg = 0; seg < 16; ++seg) vs += vpart[((size_t)bh * 16 + seg) * 64 + dd];
        float tsum = 0.f;
        for (int ii = 0; ii < U_; ++ii) tsum += topout[((size_t)bh * U_ + ii) * 64 + dd];
        cm[hd] = (0.98046875f * vs + tsum) * (1.0f / 2048.0f);   // 2008/2048
    }
    __syncthreads();
    float x[2];
    #pragma unroll
    for (int p = 0; p < 2; ++p) {
        int j = t + p * 256;
        float acc = bo[j];
        for (int c = 0; c < 128; ++c) {
            float4 cv = *(const float4*)&cm[c * 4];
            acc += cv.x * Wo[(size_t)(c * 4 + 0) * 512 + j];
            acc += cv.y * Wo[(size_t)(c * 4 + 1) * 512 + j];
            acc += cv.z * Wo[(size_t)(c * 4 + 2) * 512 + j];
            acc += cv.w * Wo[(size_t)(c * 4 + 3) * 512 + j];
        }
        x[p] = 2.0f * acc;           // a + dropout(a) = 2a in eval
    }
    rs[t] = x[0] + x[1];
    rq[t] = x[0] * x[0] + x[1] * x[1];
    __syncthreads();
    for (int str = 128; str > 0; str >>= 1) {
        if (t < str) { rs[t] += rs[t + str]; rq[t] += rq[t + str]; }
        __syncthreads();
    }
    float mean = rs[0] * (1.0f / 512.0f);
    float var  = rq[0] * (1.0f / 512.0f) - mean * mean;
    float rstd = rsqrtf(var + 1e-5f);
    #pragma unroll
    for (int p = 0; p < 2; ++p) {
        int j = t + p * 256;
        a2[b * 512 + j] = (x[p] - mean) * rstd * g1[j] + be1[j];
    }
}

// ---------------- Kernel I: ff1 partials over c-segments (grid 32x4) ----------------
__global__ void k_ff1p(const float* __restrict__ a2, const float* __restrict__ W1,
                       float* __restrict__ ffp) {
    __shared__ float Ws[64 * 132];   // 64 j x 128 c, pad 132
    __shared__ float as[8 * 128];
    int t = threadIdx.x;
    int jb = blockIdx.x, seg = blockIdx.y;
    int j0 = jb * 64, c0 = seg * 128;
    #pragma unroll
    for (int i = 0; i < 8; ++i) {
        int e = t + i * 256;         // 2048 float4
        int r = e >> 5, c4 = e & 31;
        *(float4*)&Ws[r * 132 + c4 * 4] =
            *(const float4*)&W1[(size_t)(j0 + r) * 512 + c0 + c4 * 4];
    }
    for (int e = t; e < 1024; e += 256) {
        int b = e >> 7, c = e & 127;
        as[b * 128 + c] = a2[b * 512 + c0 + c];
    }
    __syncthreads();
    int j = t & 63, bp = t >> 6;
    float acc0 = 0.f, acc1 = 0.f;
    for (int c = 0; c < 32; ++c) {
        float4 w  = *(float4*)&Ws[j * 132 + c * 4];
        float4 xa = *(float4*)&as[(bp * 2) * 128 + c * 4];
        float4 xb = *(float4*)&as[(bp * 2 + 1) * 128 + c * 4];
        acc0 += w.x * xa.x + w.y * xa.y + w.z * xa.z + w.w * xa.w;
        acc1 += w.x * xb.x + w.y * xb.y + w.z * xb.z + w.w * xb.w;
    }
    ffp[(size_t)(seg * 8 + bp * 2) * 2048 + j0 + j]     = acc0;
    ffp[(size_t)(seg * 8 + bp * 2 + 1) * 2048 + j0 + j] = acc1;
}

// ---------------- Kernel J1: ff2 partials; ff1-reduce+bias+relu fused in staging ----
__global__ void k_ff2p(const float* __restrict__ ffp, const float* __restrict__ b1v,
                       const float* __restrict__ W2, float* __restrict__ ff2p) {
    __shared__ float Ws[32 * 260];   // 32 d x 256 c, pad 260
    __shared__ float fs[8 * 256];
    int t = threadIdx.x;
    int db = blockIdx.x, seg = blockIdx.y;
    int d0 = db * 32, c0 = seg * 256;
    #pragma unroll
    for (int i = 0; i < 8; ++i) {
        int e = t + i * 256;         // 2048 float4
        int r = e >> 6, c4 = e & 63;
        *(float4*)&Ws[r * 260 + c4 * 4] =
            *(const float4*)&W2[(size_t)(d0 + r) * 2048 + c0 + c4 * 4];
    }
    for (int e = t; e < 2048; e += 256) {
        int b = e >> 8, c = e & 255;
        float s = b1v[c0 + c];
        #pragma unroll
        for (int sg = 0; sg < 4; ++sg) s += ffp[(size_t)(sg * 8 + b) * 2048 + c0 + c];
        fs[b * 256 + c] = fmaxf(s, 0.f);   // relu(ff1)
    }
    __syncthreads();
    int d = t & 31, b = t >> 5;
    float acc = 0.f;
    for (int c = 0; c < 64; ++c) {
        float4 w = *(float4*)&Ws[d * 260 + c * 4];
        float4 x = *(float4*)&fs[b * 256 + c * 4];
        acc += w.x * x.x + w.y * x.y + w.z * x.z + w.w * x.w;
    }
    ff2p[(size_t)(seg * 8 + b) * 512 + d0 + d] = acc;
}

// ---------------- Kernel J2: out = LN2(a2 + ff2); forecast = out@Wout + bout ----------
__global__ void k_final(const float* __restrict__ a2, const float* __restrict__ ff2p,
                        const float* __restrict__ b2v,
                        const float* __restrict__ g2, const float* __restrict__ be2,
                        const float* __restrict__ Wout, const float* __restrict__ bout,
                        float* __restrict__ dout) {
    __shared__ float rs[256], rq[256];
    int t = threadIdx.x, b = blockIdx.x;
    float f0 = b2v[t], f1 = b2v[t + 256];
    #pragma unroll
    for (int seg = 0; seg < 8; ++seg) {
        f0 += ff2p[(size_t)(seg * 8 + b) * 512 + t];
        f1 += ff2p[(size_t)(seg * 8 + b) * 512 + t + 256];
    }
    float x0 = a2[b * 512 + t] + f0;
    float x1 = a2[b * 512 + t + 256] + f1;
    rs[t] = x0 + x1;
    rq[t] = x0 * x0 + x1 * x1;
    __syncthreads();
    for (int str = 128; str > 0; str >>= 1) {
        if (t < str) { rs[t] += rs[t + str]; rq[t] += rq[t + str]; }
        __syncthreads();
    }
    float mean = rs[0] * (1.0f / 512.0f);
    float var  = rq[0] * (1.0f / 512.0f) - mean * mean;
    float rstd = rsqrtf(var + 1e-5f);
    float o0 = (x0 - mean) * rstd * g2[t]       + be2[t];
    float o1 = (x1 - mean) * rstd * g2[t + 256] + be2[t + 256];
    dout[8 + b * 512 + t]       = o0;
    dout[8 + b * 512 + t + 256] = o1;
    __syncthreads();
    rs[t] = o0 * Wout[t] + o1 * Wout[t + 256];
    __syncthreads();
    for (int str = 128; str > 0; str >>= 1) {
        if (t < str) rs[t] += rs[t + str];
        __syncthreads();
    }
    if (t == 0) dout[b] = rs[0] + bout[0];
}

extern "C" void kernel_launch(void* const* d_in, const int* in_sizes, int n_in,
                              void* d_out, int out_size, void* d_ws, size_t ws_size,
                              hipStream_t stream) {
    const float* X    = (const float*)d_in[0];
    const float* Wq   = (const float*)d_in[1];
    const float* bq   = (const float*)d_in[2];
    const float* Wk   = (const float*)d_in[3];
    const float* bk   = (const float*)d_in[4];
    const float* Wv   = (const float*)d_in[5];
    const float* bv   = (const float*)d_in[6];
    const float* Wo   = (const float*)d_in[7];
    const float* bo   = (const float*)d_in[8];
    const float* W1   = (const float*)d_in[9];
    const float* b1   = (const float*)d_in[10];
    const float* W2   = (const float*)d_in[11];
    const float* b2   = (const float*)d_in[12];
    const float* g1   = (const float*)d_in[13];
    const float* be1  = (const float*)d_in[14];
    const float* g2   = (const float*)d_in[15];
    const float* be2  = (const float*)d_in[16];
    const float* Wout = (const float*)d_in[17];
    const float* bout = (const float*)d_in[18];
    float* out = (float*)d_out;

    char* ws = (char*)d_ws;
    size_t off = 0;
    auto alloc = [&](size_t bytes) -> void* {
        void* p = ws + off;
        off += (bytes + 255) & ~(size_t)255;
        return p;
    };
    bf16_t* Xb   = (bf16_t*)alloc((size_t)NM_ * D_ * 2);          // 16.8 MB
    bf16_t* WT   = (bf16_t*)alloc((size_t)1536 * 512 * 2);        //  1.6 MB
    bf16_t* Qb   = (bf16_t*)alloc((size_t)BH_ * L_ * DH_ * 2);    // 16.8 MB
    bf16_t* Kb   = (bf16_t*)alloc((size_t)BH_ * L_ * DH_ * 2);    // 16.8 MB
    bf16_t* Vb   = (bf16_t*)alloc((size_t)BH_ * L_ * DH_ * 2);    // 16.8 MB
    float*  Mv   = (float*) alloc((size_t)BH_ * L_ * 4);
    float*  kpart= (float*) alloc((size_t)BH_ * 16 * 64 * 4);     // 256 KB
    float*  vpart= (float*) alloc((size_t)BH_ * 16 * 64 * 4);     // 256 KB
    int*    tidx = (int*)   alloc((size_t)BH_ * U_ * 4);
    float*  tout = (float*) alloc((size_t)BH_ * U_ * 64 * 4);
    float*  a2   = (float*) alloc(8 * 512 * 4);
    float*  ffp  = (float*) alloc((size_t)4 * 8 * 2048 * 4);      // 256 KB
    float*  ff2p = (float*) alloc((size_t)8 * 8 * 512 * 4);       // 128 KB
    // attention partials (64*16*40*66 fp32 = 10.8 MB) alias the dead Xb region
    float*  part = (float*)Xb;    // Xb is consumed by k_qkv before k_attn2 runs
    (void)ws_size; (void)in_sizes; (void)n_in; (void)out_size;

    hipLaunchKernelGGL(k_prep,    dim3(4096 + 192), dim3(256), 0, stream, X, Xb, Wq, Wk, Wv, WT);
    hipLaunchKernelGGL(k_qkv,     dim3(12, 128),    dim3(256), 0, stream, Xb, WT, bq, bk, bv, Qb, Kb, Vb, kpart, vpart);
    hipLaunchKernelGGL(k_rowmax,  dim3(16, 64),     dim3(256), 0, stream, Qb, Kb, kpart, Mv);
    hipLaunchKernelGGL(k_topk,    dim3(64),         dim3(64),  0, stream, Mv, tidx);
    hipLaunchKernelGGL(k_attn2,   dim3(NCK_, 64),   dim3(256), 0, stream, Qb, Kb, Vb, tidx, part);
    hipLaunchKernelGGL(k_attnred, dim3(64),         dim3(256), 0, stream, part, tout);
    hipLaunchKernelGGL(k_ctx,     dim3(8),          dim3(256), 0, stream, vpart, tout, Wo, bo, g1, be1, a2);
    hipLaunchKernelGGL(k_ff1p,    dim3(32, 4),      dim3(256), 0, stream, a2, W1, ffp);
    hipLaunchKernelGGL(k_ff2p,    dim3(16, 8),      dim3(256), 0, stream, ffp, b1, W2, ff2p);
    hipLaunchKernelGGL(k_final,   dim3(8),          dim3(256), 0, stream, a2, ff2p, b2, g2, be2, Wout, bout, out);
}

// Round 13
// 291.769 us; speedup vs baseline: 1.2566x; 1.0170x over previous
//
#include <hip/hip_runtime.h>
#include <hip/hip_bf16.h>

// SparseDecoder (Informer ProbSparse) for MI355X.
// B=8 L=2048 D=512 H=8 dh=64 DFF=2048 u=40.
// R4: radix-select topk. R6: attn on MFMA; ff split-K. R7-R9: conflict-free
// XOR-swizzled LDS; reg-mediated staging (gl_lds + swizzled src breaks coalescing).
// R10: k_sums fused into k_qkv; V bf16; 10 launches.
// R11 FAILED: LDS-free k_rowmax 47->124us (every wave re-pulls K from L2 at
//   ~200cyc; LDS reuse is essential). R12: reverted; k_qkv launch_bounds(256,6).
// R13: k_rowmax Q-tile 128->256 rows/block (rf=4, grid (8,64)): K staged 8x
//   per bh instead of 16x; 2x MFMA per ds_read.

#define B_   8
#define L_   2048
#define D_   512
#define H_   8
#define DH_  64
#define DFF_ 2048
#define U_   40
#define BH_  64
#define NM_  16384   // B*L
#define NCK_ 16      // key chunks in k_attn2
#define CKS_ 128     // keys per chunk

typedef __bf16 bf16_t;
typedef __bf16 bf16x8 __attribute__((ext_vector_type(8)));
typedef float  f32x4  __attribute__((ext_vector_type(4)));

// ---------------- Kernel A: X fp32 -> bf16 ; + W transpose (merged) ----------------
__global__ void k_prep(const float* __restrict__ X, bf16_t* __restrict__ Xb,
                       const float* __restrict__ Wq, const float* __restrict__ Wk,
                       const float* __restrict__ Wv, bf16_t* __restrict__ WT) {
    __shared__ float tile[64][65];
    int t = threadIdx.x;
    if (blockIdx.x < 4096) {
        size_t g = (size_t)blockIdx.x * 256 + t;
        const float4* xp = (const float4*)&X[g * 8];
        float4 f0 = xp[0], f1 = xp[1];
        bf16x8 hv;
        hv[0]=(bf16_t)f0.x; hv[1]=(bf16_t)f0.y; hv[2]=(bf16_t)f0.z; hv[3]=(bf16_t)f0.w;
        hv[4]=(bf16_t)f1.x; hv[5]=(bf16_t)f1.y; hv[6]=(bf16_t)f1.z; hv[7]=(bf16_t)f1.w;
        *(bf16x8*)&Xb[g * 8] = hv;
        return;
    }
    int blk = blockIdx.x - 4096;     // 192 = 3 mats * 64 tiles
    int mat = blk >> 6, tl = blk & 63;
    int tr = (tl >> 3) << 6;
    int tc = (tl & 7) << 6;
    const float* W = (mat == 0) ? Wq : (mat == 1) ? Wk : Wv;
    #pragma unroll
    for (int i = 0; i < 16; ++i) {
        int e = t + i * 256, r = e >> 6, c = e & 63;
        tile[r][c] = W[(size_t)(tr + r) * 512 + tc + c];
    }
    __syncthreads();
    #pragma unroll
    for (int i = 0; i < 16; ++i) {
        int e = t + i * 256, r = e >> 6, c = e & 63;
        WT[(size_t)(mat * 512 + tc + r) * 512 + tr + c] = (bf16_t)tile[c][r];
    }
}

// ---------------- Kernel C: QKV projection GEMM + fused ksum/vsum partials --------
// Linear coalesced global loads -> XOR-swizzled ds_write -> conflict-free reads.
__global__ __launch_bounds__(256, 6) void k_qkv(const bf16_t* __restrict__ Xb,
        const bf16_t* __restrict__ WT,
        const float* __restrict__ bq, const float* __restrict__ bk, const float* __restrict__ bv,
        bf16_t* __restrict__ Qb, bf16_t* __restrict__ Kb, bf16_t* __restrict__ Vb,
        float* __restrict__ kpart, float* __restrict__ vpart) {
    __shared__ bf16_t As[128 * 64];  // slot (r,cs^(r&7)) holds chunk cs of row r
    __shared__ bf16_t Bs[128 * 64];
    int t = threadIdx.x;
    int m0 = blockIdx.y * 128;
    int n0 = blockIdx.x * 128;
    int wv = t >> 6, lane = t & 63, lr = lane & 15, qd = lane >> 4;
    int wm = (wv & 1) * 64, wn = (wv >> 1) * 64;
    f32x4 acc[4][4];
    #pragma unroll
    for (int a = 0; a < 4; ++a)
        #pragma unroll
        for (int b = 0; b < 4; ++b) acc[a][b] = (f32x4){0.f, 0.f, 0.f, 0.f};

    for (int kt = 0; kt < 8; ++kt) {
        // coalesced global -> regs (overlaps with previous iter's MFMAs)
        bf16x8 areg[4], breg[4];
        #pragma unroll
        for (int i = 0; i < 4; ++i) {
            int ch = i * 256 + t, r = ch >> 3, cs = ch & 7;
            areg[i] = *(const bf16x8*)&Xb[(size_t)(m0 + r) * 512 + kt * 64 + cs * 8];
            breg[i] = *(const bf16x8*)&WT[(size_t)(n0 + r) * 512 + kt * 64 + cs * 8];
        }
        __syncthreads();             // prev iter frag reads complete
        #pragma unroll
        for (int i = 0; i < 4; ++i) {
            int ch = i * 256 + t, r = ch >> 3, cs = ch & 7, c = cs ^ (r & 7);
            *(bf16x8*)&As[(r * 8 + c) * 8] = areg[i];
            *(bf16x8*)&Bs[(r * 8 + c) * 8] = breg[i];
        }
        __syncthreads();
        bf16x8 af[4][2], bfg[4][2];
        #pragma unroll
        for (int rf = 0; rf < 4; ++rf) {
            int row = wm + rf * 16 + lr;
            #pragma unroll
            for (int ks = 0; ks < 2; ++ks)
                af[rf][ks] = *(bf16x8*)&As[row * 64 + (((ks * 4 + qd) ^ (row & 7)) * 8)];
        }
        #pragma unroll
        for (int cf = 0; cf < 4; ++cf) {
            int row = wn + cf * 16 + lr;
            #pragma unroll
            for (int ks = 0; ks < 2; ++ks)
                bfg[cf][ks] = *(bf16x8*)&Bs[row * 64 + (((ks * 4 + qd) ^ (row & 7)) * 8)];
        }
        #pragma unroll
        for (int cf = 0; cf < 4; ++cf)
            #pragma unroll
            for (int rf = 0; rf < 4; ++rf) {
                acc[rf][cf] = __builtin_amdgcn_mfma_f32_16x16x32_bf16(af[rf][0], bfg[cf][0], acc[rf][cf], 0, 0, 0);
                acc[rf][cf] = __builtin_amdgcn_mfma_f32_16x16x32_bf16(af[rf][1], bfg[cf][1], acc[rf][cf], 0, 0, 0);
            }
    }
    int sec = n0 >> 9;               // 0=Q 1=K 2=V (128-tile never straddles)
    const float* bias = (sec == 0) ? bq : (sec == 1) ? bk : bv;
    float colsum[4] = {0.f, 0.f, 0.f, 0.f};
    #pragma unroll
    for (int rf = 0; rf < 4; ++rf) {
        #pragma unroll
        for (int r = 0; r < 4; ++r) {
            int m = m0 + wm + rf * 16 + qd * 4 + r;          // C row = quad*4+reg
            int b = m >> 11, l = m & 2047;
            #pragma unroll
            for (int cf = 0; cf < 4; ++cf) {
                int n = n0 + wn + cf * 16 + lr;              // C col = lane&15
                int nn = n & 511;
                int h = nn >> 6, d = nn & 63;
                float val = acc[rf][cf][r] + bias[nn];
                colsum[cf] += val;
                size_t oidx = ((size_t)(b * 8 + h) * L_ + l) * 64 + d;
                if (sec == 0)      Qb[oidx] = (bf16_t)val;
                else if (sec == 1) Kb[oidx] = (bf16_t)val;
                else               Vb[oidx] = (bf16_t)val;
            }
        }
    }
    if (sec != 0) {                  // fused column-sum partials (fp32, pre-round)
        float* sred = (float*)As;    // alias: 128 n x 8 groups (4 KB)
        __syncthreads();             // all frag reads long done; make alias safe
        int g = (wv & 1) * 4 + qd;
        #pragma unroll
        for (int cf = 0; cf < 4; ++cf)
            sred[(wn + cf * 16 + lr) * 8 + g] = colsum[cf];
        __syncthreads();
        if (t < 128) {
            float s = 0.f;
            #pragma unroll
            for (int gg = 0; gg < 8; ++gg) s += sred[t * 8 + gg];
            int nn = (n0 + t) & 511;
            int h = nn >> 6, d = nn & 63;
            int b = blockIdx.y >> 4, seg = blockIdx.y & 15;
            float* dst = (sec == 1) ? kpart : vpart;
            dst[(((size_t)(b * 8 + h)) * 16 + seg) * 64 + d] = s;
        }
    }
}

// ---------------- Kernel D: rowmax of Q@K^T + fused M ----------------
// grid (8, 64): 256 Q rows per block (rf=4). Reg-mediated swizzled K staging;
// K staged 8x per bh (was 16x), 2x MFMA per ds_read.
__global__ __launch_bounds__(256) void k_rowmax(const bf16_t* __restrict__ Qb,
        const bf16_t* __restrict__ Kb, const float* __restrict__ kpart,
        float* __restrict__ Mv) {
    __shared__ bf16_t Ks[128 * 64];  // XOR-swizzled layout
    __shared__ float ksum_s[64];
    __shared__ float dot_s[256];
    int t = threadIdx.x;
    int bh = blockIdx.y;
    int row0 = blockIdx.x * 256;
    int wv = t >> 6, lane = t & 63, lr = lane & 15, qd = lane >> 4;
    size_t base = (size_t)bh * L_ * DH_;
    if (t < 64) {
        float a = 0.f;
        #pragma unroll
        for (int seg = 0; seg < 16; ++seg) a += kpart[((size_t)bh * 16 + seg) * 64 + t];
        ksum_s[t] = a;
    }
    bf16x8 af[4][2];                 // Q-frags pinned (rows wv*64+rf*16+lr)
    #pragma unroll
    for (int rf = 0; rf < 4; ++rf)
        #pragma unroll
        for (int ks = 0; ks < 2; ++ks)
            af[rf][ks] = *(const bf16x8*)&Qb[base + (size_t)(row0 + wv * 64 + rf * 16 + lr) * 64 + ks * 32 + qd * 8];
    __syncthreads();                 // ksum_s ready
    // fused M dot: q . ksum per A-layout row (rf*16+lr); reduce across qd lanes
    #pragma unroll
    for (int rf = 0; rf < 4; ++rf) {
        float v = 0.f;
        #pragma unroll
        for (int ks = 0; ks < 2; ++ks)
            #pragma unroll
            for (int j = 0; j < 8; ++j)
                v += (float)af[rf][ks][j] * ksum_s[ks * 32 + qd * 8 + j];
        v += __shfl_xor(v, 16);
        v += __shfl_xor(v, 32);
        if (qd == 0) dot_s[wv * 64 + rf * 16 + lr] = v;   // same-wave write/read: no barrier
    }
    float pmax[4][4];
    #pragma unroll
    for (int a = 0; a < 4; ++a)
        #pragma unroll
        for (int r = 0; r < 4; ++r) pmax[a][r] = -3.4e38f;

    for (int cb = 0; cb < 16; ++cb) {
        bf16x8 kreg[4];              // coalesced global -> regs
        #pragma unroll
        for (int i = 0; i < 4; ++i) {
            int ch = i * 256 + t, r = ch >> 3, cs = ch & 7;
            kreg[i] = *(const bf16x8*)&Kb[base + (size_t)(cb * 128 + r) * 64 + cs * 8];
        }
        __syncthreads();
        #pragma unroll
        for (int i = 0; i < 4; ++i) {
            int ch = i * 256 + t, r = ch >> 3, cs = ch & 7, c = cs ^ (r & 7);
            *(bf16x8*)&Ks[(r * 8 + c) * 8] = kreg[i];
        }
        __syncthreads();
        #pragma unroll
        for (int cf = 0; cf < 8; cf += 2) {
            int keyA = cf * 16 + lr, keyB = (cf + 1) * 16 + lr;
            bf16x8 bA0 = *(bf16x8*)&Ks[keyA * 64 + ((qd ^ (keyA & 7)) * 8)];
            bf16x8 bA1 = *(bf16x8*)&Ks[keyA * 64 + (((4 + qd) ^ (keyA & 7)) * 8)];
            bf16x8 bB0 = *(bf16x8*)&Ks[keyB * 64 + ((qd ^ (keyB & 7)) * 8)];
            bf16x8 bB1 = *(bf16x8*)&Ks[keyB * 64 + (((4 + qd) ^ (keyB & 7)) * 8)];
            #pragma unroll
            for (int rf = 0; rf < 4; ++rf) {
                f32x4 z = {0.f, 0.f, 0.f, 0.f};
                f32x4 c0 = __builtin_amdgcn_mfma_f32_16x16x32_bf16(af[rf][0], bA0, z, 0, 0, 0);
                c0 = __builtin_amdgcn_mfma_f32_16x16x32_bf16(af[rf][1], bA1, c0, 0, 0, 0);
                f32x4 c1 = __builtin_amdgcn_mfma_f32_16x16x32_bf16(af[rf][0], bB0, z, 0, 0, 0);
                c1 = __builtin_amdgcn_mfma_f32_16x16x32_bf16(af[rf][1], bB1, c1, 0, 0, 0);
                #pragma unroll
                for (int r = 0; r < 4; ++r)
                    pmax[rf][r] = fmaxf(pmax[rf][r], fmaxf(c0[r], c1[r]));
            }
        }
    }
    #pragma unroll
    for (int rf = 0; rf < 4; ++rf)
        #pragma unroll
        for (int r = 0; r < 4; ++r) {
            float v = pmax[rf][r];
            v = fmaxf(v, __shfl_xor(v, 1));
            v = fmaxf(v, __shfl_xor(v, 2));
            v = fmaxf(v, __shfl_xor(v, 4));
            v = fmaxf(v, __shfl_xor(v, 8));
            if (lr == 0) {
                int row = wv * 64 + rf * 16 + qd * 4 + r;
                Mv[bh * L_ + row0 + row] = v - dot_s[row] * (1.0f / 2048.0f);
            }
        }
}

// ---------------- Kernel F: top-40 via binary-search radix select ----------------
__global__ void k_topk(const float* __restrict__ Mv, int* __restrict__ topidx) {
    int lane = threadIdx.x;          // 64 threads
    int bh = blockIdx.x;
    unsigned key[32];
    #pragma unroll
    for (int j = 0; j < 32; ++j) {
        unsigned b = __float_as_uint(Mv[bh * L_ + j * 64 + lane]);
        key[j] = (b & 0x80000000u) ? ~b : (b | 0x80000000u);   // monotone map
    }
    unsigned lo = 0u, hi = 0xFFFFFFFFu;
    while (lo < hi) {
        unsigned mid = lo + ((hi - lo) >> 1) + 1;
        int c = 0;
        #pragma unroll
        for (int j = 0; j < 32; ++j)
            c += __popcll(__ballot(key[j] >= mid));
        if (c >= U_) lo = mid; else hi = mid - 1;
    }
    unsigned K40 = lo;
    int c_gt = 0;
    #pragma unroll
    for (int j = 0; j < 32; ++j)
        c_gt += __popcll(__ballot(key[j] > K40));
    unsigned long long lmask = (1ull << lane) - 1ull;
    int base_gt = 0, base_eq = 0;
    #pragma unroll
    for (int j = 0; j < 32; ++j) {
        bool gt = key[j] > K40, eq = key[j] == K40;
        unsigned long long mg = __ballot(gt);
        unsigned long long me = __ballot(eq);
        if (gt) {
            int pos = base_gt + __popcll(mg & lmask);
            topidx[bh * U_ + pos] = j * 64 + lane;
        } else if (eq) {
            int ep = base_eq + __popcll(me & lmask);
            if (c_gt + ep < U_)
                topidx[bh * U_ + c_gt + ep] = j * 64 + lane;
        }
        base_gt += __popcll(mg);
        base_eq += __popcll(me);
    }
}

// ---------------- Kernel G: MFMA flash-chunk attention partials ----------------
__global__ __launch_bounds__(256) void k_attn2(const bf16_t* __restrict__ Qb,
        const bf16_t* __restrict__ Kb, const bf16_t* __restrict__ Vb,
        const int* __restrict__ topidx, float* __restrict__ part) {
    __shared__ bf16_t Qs[48 * 72];       // padded (stride 72): 2-way free reads
    __shared__ bf16_t Ks[128 * 64];      // XOR-swizzled; later aliased by P
    __shared__ bf16_t Vt[64 * 136];      // V^T [d][key], pad 136
    __shared__ float  wred[4][48];
    __shared__ float  frow[48];
    __shared__ int    tid_s[40];
    bf16_t* Ps = Ks;                     // P[48][136] = 13056 bf16 <= 16384 (alias)

    int t = threadIdx.x;
    int ck = blockIdx.x, bh = blockIdx.y;
    int c0 = ck * CKS_;
    size_t base = (size_t)bh * L_ * DH_;
    if (t < 40) tid_s[t] = topidx[bh * U_ + t];
    // K: coalesced global -> regs -> XOR-swizzled LDS (R8 lesson)
    bf16x8 kreg[4];
    #pragma unroll
    for (int i = 0; i < 4; ++i) {
        int s = i * 256 + t, r = s >> 3, cs = s & 7;
        kreg[i] = *(const bf16x8*)&Kb[base + (size_t)(c0 + r) * 64 + cs * 8];
    }
    #pragma unroll
    for (int i = 0; i < 4; ++i) {
        int s = i * 256 + t, r = s >> 3, cs = s & 7, c = cs ^ (r & 7);
        *(bf16x8*)&Ks[(r * 8 + c) * 8] = kreg[i];
    }
    __syncthreads();                     // tid_s ready (Q gather needs it)
    for (int e = t; e < 48 * 8; e += 256) {
        int r = e >> 3, c8 = e & 7;
        bf16x8 v;
        #pragma unroll
        for (int j = 0; j < 8; ++j) v[j] = (bf16_t)0.f;
        if (r < 40) v = *(const bf16x8*)&Qb[base + (size_t)tid_s[r] * 64 + c8 * 8];
        *(bf16x8*)&Qs[r * 72 + c8 * 8] = v;
    }
    // V^T build from bf16 V: coalesced bf16x8 reads, scalar LDS writes
    #pragma unroll
    for (int i = 0; i < 4; ++i) {
        int e = t + i * 256;             // 1024 chunks: 128 keys x 8
        int key = e >> 3, c8 = e & 7;
        bf16x8 v = *(const bf16x8*)&Vb[base + (size_t)(c0 + key) * 64 + c8 * 8];
        #pragma unroll
        for (int j = 0; j < 8; ++j)
            Vt[(c8 * 8 + j) * 136 + key] = v[j];
    }
    __syncthreads();

    int wv = t >> 6, lane = t & 63, lr = lane & 15, qd = lane >> 4;
    bf16x8 aq[3][2];
    #pragma unroll
    for (int tm = 0; tm < 3; ++tm)
        #pragma unroll
        for (int ks = 0; ks < 2; ++ks)
            aq[tm][ks] = *(bf16x8*)&Qs[(tm * 16 + lr) * 72 + ks * 32 + qd * 8];
    f32x4 S[3][2];
    #pragma unroll
    for (int nt = 0; nt < 2; ++nt) {
        int key = wv * 32 + nt * 16 + lr;
        bf16x8 bk0 = *(bf16x8*)&Ks[key * 64 + ((qd ^ (key & 7)) * 8)];
        bf16x8 bk1 = *(bf16x8*)&Ks[key * 64 + (((4 + qd) ^ (key & 7)) * 8)];
        #pragma unroll
        for (int tm = 0; tm < 3; ++tm) {
            f32x4 z = {0.f, 0.f, 0.f, 0.f};
            z = __builtin_amdgcn_mfma_f32_16x16x32_bf16(aq[tm][0], bk0, z, 0, 0, 0);
            S[tm][nt] = __builtin_amdgcn_mfma_f32_16x16x32_bf16(aq[tm][1], bk1, z, 0, 0, 0);
        }
    }
    float rm[3][4];
    #pragma unroll
    for (int tm = 0; tm < 3; ++tm)
        #pragma unroll
        for (int r = 0; r < 4; ++r) {
            float v = fmaxf(S[tm][0][r], S[tm][1][r]);
            v = fmaxf(v, __shfl_xor(v, 1));
            v = fmaxf(v, __shfl_xor(v, 2));
            v = fmaxf(v, __shfl_xor(v, 4));
            v = fmaxf(v, __shfl_xor(v, 8));
            rm[tm][r] = v;
        }
    if (lr == 0) {
        #pragma unroll
        for (int tm = 0; tm < 3; ++tm)
            #pragma unroll
            for (int r = 0; r < 4; ++r)
                wred[wv][tm * 16 + qd * 4 + r] = rm[tm][r];
    }
    __syncthreads();
    if (t < 48)
        frow[t] = fmaxf(fmaxf(wred[0][t], wred[1][t]), fmaxf(wred[2][t], wred[3][t]));
    __syncthreads();
    float rs_[3][4];
    #pragma unroll
    for (int tm = 0; tm < 3; ++tm) {
        #pragma unroll
        for (int r = 0; r < 4; ++r) {
            float fm = frow[tm * 16 + qd * 4 + r];
            float s0 = __expf((S[tm][0][r] - fm) * 0.125f);
            float s1 = __expf((S[tm][1][r] - fm) * 0.125f);
            Ps[(tm * 16 + qd * 4 + r) * 136 + wv * 32 + lr]      = (bf16_t)s0;
            Ps[(tm * 16 + qd * 4 + r) * 136 + wv * 32 + 16 + lr] = (bf16_t)s1;
            rs_[tm][r] = s0 + s1;
        }
    }
    #pragma unroll
    for (int tm = 0; tm < 3; ++tm)
        #pragma unroll
        for (int r = 0; r < 4; ++r) {
            float v = rs_[tm][r];
            v += __shfl_xor(v, 1);
            v += __shfl_xor(v, 2);
            v += __shfl_xor(v, 4);
            v += __shfl_xor(v, 8);
            rs_[tm][r] = v;
        }
    if (lr == 0) {
        #pragma unroll
        for (int tm = 0; tm < 3; ++tm)
            #pragma unroll
            for (int r = 0; r < 4; ++r)
                wred[wv][tm * 16 + qd * 4 + r] = rs_[tm][r];
    }
    __syncthreads();
    float* pb = &part[(((size_t)bh * NCK_ + ck) * 40) * 66];
    if (t < 40) {
        pb[t * 66 + 64] = frow[t] * 0.125f;   // m in scaled units
        pb[t * 66 + 65] = wred[0][t] + wred[1][t] + wred[2][t] + wred[3][t];
    }
    f32x4 O[3];
    #pragma unroll
    for (int tm = 0; tm < 3; ++tm) O[tm] = (f32x4){0.f, 0.f, 0.f, 0.f};
    #pragma unroll
    for (int kk = 0; kk < 4; ++kk) {
        bf16x8 bv = *(bf16x8*)&Vt[(wv * 16 + lr) * 136 + kk * 32 + qd * 8];
        #pragma unroll
        for (int tm = 0; tm < 3; ++tm) {
            bf16x8 ap = *(bf16x8*)&Ps[(tm * 16 + lr) * 136 + kk * 32 + qd * 8];
            O[tm] = __builtin_amdgcn_mfma_f32_16x16x32_bf16(ap, bv, O[tm], 0, 0, 0);
        }
    }
    #pragma unroll
    for (int tm = 0; tm < 3; ++tm)
        #pragma unroll
        for (int r = 0; r < 4; ++r) {
            int row = tm * 16 + qd * 4 + r;
            if (row < 40) pb[row * 66 + wv * 16 + lr] = O[tm][r];
        }
}

// ---------------- Kernel G2: combine chunk partials -> topout ----------------
__global__ void k_attnred(const float* __restrict__ part, float* __restrict__ tout) {
    int t = threadIdx.x, bh = blockIdx.x;
    int d = t & 63, rg = t >> 6;
    const float* pb0 = &part[((size_t)bh * NCK_) * 40 * 66];
    for (int ri = 0; ri < 10; ++ri) {
        int r = rg + 4 * ri;
        float M = -3.4e38f;
        #pragma unroll
        for (int c = 0; c < NCK_; ++c) M = fmaxf(M, pb0[(c * 40 + r) * 66 + 64]);
        float lsum = 0.f, osum = 0.f;
        #pragma unroll
        for (int c = 0; c < NCK_; ++c) {
            float w = __expf(pb0[(c * 40 + r) * 66 + 64] - M);
            lsum += w * pb0[(c * 40 + r) * 66 + 65];
            osum += w * pb0[(c * 40 + r) * 66 + d];
        }
        tout[((size_t)bh * U_ + r) * 64 + d] = osum / lsum;
    }
}

// ---------------- Kernel H: ctx-mean -> @Wo+bo -> LN1(2a) -> a2 ----------------
__global__ void k_ctx(const float* __restrict__ vpart, const float* __restrict__ topout,
                      const float* __restrict__ Wo, const float* __restrict__ bo,
                      const float* __restrict__ g1, const float* __restrict__ be1,
                      float* __restrict__ a2) {
    __shared__ float cm[512];
    __shared__ float rs[256], rq[256];
    int t = threadIdx.x, b = blockIdx.x;
    #pragma unroll
    for (int p = 0; p < 2; ++p) {
        int hd = t + p * 256;
        int h = hd >> 6, dd = hd & 63;
        int bh = b * 8 + h;
        float vs = 0.f;
        #pragma unroll
        for (int seg = 0; seg < 16; ++seg) vs += vpart[((size_t)bh * 16 + seg) * 64 + dd];
        float tsum = 0.f;
        for (int ii = 0; ii < U_; ++ii) tsum += topout[((size_t)bh * U_ + ii) * 64 + dd];
        cm[hd] = (0.98046875f * vs + tsum) * (1.0f / 2048.0f);   // 2008/2048
    }
    __syncthreads();
    float x[2];
    #pragma unroll
    for (int p = 0; p < 2; ++p) {
        int j = t + p * 256;
        float acc = bo[j];
        for (int c = 0; c < 128; ++c) {
            float4 cv = *(const float4*)&cm[c * 4];
            acc += cv.x * Wo[(size_t)(c * 4 + 0) * 512 + j];
            acc += cv.y * Wo[(size_t)(c * 4 + 1) * 512 + j];
            acc += cv.z * Wo[(size_t)(c * 4 + 2) * 512 + j];
            acc += cv.w * Wo[(size_t)(c * 4 + 3) * 512 + j];
        }
        x[p] = 2.0f * acc;           // a + dropout(a) = 2a in eval
    }
    rs[t] = x[0] + x[1];
    rq[t] = x[0] * x[0] + x[1] * x[1];
    __syncthreads();
    for (int str = 128; str > 0; str >>= 1) {
        if (t < str) { rs[t] += rs[t + str]; rq[t] += rq[t + str]; }
        __syncthreads();
    }
    float mean = rs[0] * (1.0f / 512.0f);
    float var  = rq[0] * (1.0f / 512.0f) - mean * mean;
    float rstd = rsqrtf(var + 1e-5f);
    #pragma unroll
    for (int p = 0; p < 2; ++p) {
        int j = t + p * 256;
        a2[b * 512 + j] = (x[p] - mean) * rstd * g1[j] + be1[j];
    }
}

// ---------------- Kernel I: ff1 partials over c-segments (grid 32x4) ----------------
__global__ void k_ff1p(const float* __restrict__ a2, const float* __restrict__ W1,
                       float* __restrict__ ffp) {
    __shared__ float Ws[64 * 132];   // 64 j x 128 c, pad 132
    __shared__ float as[8 * 128];
    int t = threadIdx.x;
    int jb = blockIdx.x, seg = blockIdx.y;
    int j0 = jb * 64, c0 = seg * 128;
    #pragma unroll
    for (int i = 0; i < 8; ++i) {
        int e = t + i * 256;         // 2048 float4
        int r = e >> 5, c4 = e & 31;
        *(float4*)&Ws[r * 132 + c4 * 4] =
            *(const float4*)&W1[(size_t)(j0 + r) * 512 + c0 + c4 * 4];
    }
    for (int e = t; e < 1024; e += 256) {
        int b = e >> 7, c = e & 127;
        as[b * 128 + c] = a2[b * 512 + c0 + c];
    }
    __syncthreads();
    int j = t & 63, bp = t >> 6;
    float acc0 = 0.f, acc1 = 0.f;
    for (int c = 0; c < 32; ++c) {
        float4 w  = *(float4*)&Ws[j * 132 + c * 4];
        float4 xa = *(float4*)&as[(bp * 2) * 128 + c * 4];
        float4 xb = *(float4*)&as[(bp * 2 + 1) * 128 + c * 4];
        acc0 += w.x * xa.x + w.y * xa.y + w.z * xa.z + w.w * xa.w;
        acc1 += w.x * xb.x + w.y * xb.y + w.z * xb.z + w.w * xb.w;
    }
    ffp[(size_t)(seg * 8 + bp * 2) * 2048 + j0 + j]     = acc0;
    ffp[(size_t)(seg * 8 + bp * 2 + 1) * 2048 + j0 + j] = acc1;
}

// ---------------- Kernel J1: ff2 partials; ff1-reduce+bias+relu fused in staging ----
__global__ void k_ff2p(const float* __restrict__ ffp, const float* __restrict__ b1v,
                       const float* __restrict__ W2, float* __restrict__ ff2p) {
    __shared__ float Ws[32 * 260];   // 32 d x 256 c, pad 260
    __shared__ float fs[8 * 256];
    int t = threadIdx.x;
    int db = blockIdx.x, seg = blockIdx.y;
    int d0 = db * 32, c0 = seg * 256;
    #pragma unroll
    for (int i = 0; i < 8; ++i) {
        int e = t + i * 256;         // 2048 float4
        int r = e >> 6, c4 = e & 63;
        *(float4*)&Ws[r * 260 + c4 * 4] =
            *(const float4*)&W2[(size_t)(d0 + r) * 2048 + c0 + c4 * 4];
    }
    for (int e = t; e < 2048; e += 256) {
        int b = e >> 8, c = e & 255;
        float s = b1v[c0 + c];
        #pragma unroll
        for (int sg = 0; sg < 4; ++sg) s += ffp[(size_t)(sg * 8 + b) * 2048 + c0 + c];
        fs[b * 256 + c] = fmaxf(s, 0.f);   // relu(ff1)
    }
    __syncthreads();
    int d = t & 31, b = t >> 5;
    float acc = 0.f;
    for (int c = 0; c < 64; ++c) {
        float4 w = *(float4*)&Ws[d * 260 + c * 4];
        float4 x = *(float4*)&fs[b * 256 + c * 4];
        acc += w.x * x.x + w.y * x.y + w.z * x.z + w.w * x.w;
    }
    ff2p[(size_t)(seg * 8 + b) * 512 + d0 + d] = acc;
}

// ---------------- Kernel J2: out = LN2(a2 + ff2); forecast = out@Wout + bout ----------
__global__ void k_final(const float* __restrict__ a2, const float* __restrict__ ff2p,
                        const float* __restrict__ b2v,
                        const float* __restrict__ g2, const float* __restrict__ be2,
                        const float* __restrict__ Wout, const float* __restrict__ bout,
                        float* __restrict__ dout) {
    __shared__ float rs[256], rq[256];
    int t = threadIdx.x, b = blockIdx.x;
    float f0 = b2v[t], f1 = b2v[t + 256];
    #pragma unroll
    for (int seg = 0; seg < 8; ++seg) {
        f0 += ff2p[(size_t)(seg * 8 + b) * 512 + t];
        f1 += ff2p[(size_t)(seg * 8 + b) * 512 + t + 256];
    }
    float x0 = a2[b * 512 + t] + f0;
    float x1 = a2[b * 512 + t + 256] + f1;
    rs[t] = x0 + x1;
    rq[t] = x0 * x0 + x1 * x1;
    __syncthreads();
    for (int str = 128; str > 0; str >>= 1) {
        if (t < str) { rs[t] += rs[t + str]; rq[t] += rq[t + str]; }
        __syncthreads();
    }
    float mean = rs[0] * (1.0f / 512.0f);
    float var  = rq[0] * (1.0f / 512.0f) - mean * mean;
    float rstd = rsqrtf(var + 1e-5f);
    float o0 = (x0 - mean) * rstd * g2[t]       + be2[t];
    float o1 = (x1 - mean) * rstd * g2[t + 256] + be2[t + 256];
    dout[8 + b * 512 + t]       = o0;
    dout[8 + b * 512 + t + 256] = o1;
    __syncthreads();
    rs[t] = o0 * Wout[t] + o1 * Wout[t + 256];
    __syncthreads();
    for (int str = 128; str > 0; str >>= 1) {
        if (t < str) rs[t] += rs[t + str];
        __syncthreads();
    }
    if (t == 0) dout[b] = rs[0] + bout[0];
}

extern "C" void kernel_launch(void* const* d_in, const int* in_sizes, int n_in,
                              void* d_out, int out_size, void* d_ws, size_t ws_size,
                              hipStream_t stream) {
    const float* X    = (const float*)d_in[0];
    const float* Wq   = (const float*)d_in[1];
    const float* bq   = (const float*)d_in[2];
    const float* Wk   = (const float*)d_in[3];
    const float* bk   = (const float*)d_in[4];
    const float* Wv   = (const float*)d_in[5];
    const float* bv   = (const float*)d_in[6];
    const float* Wo   = (const float*)d_in[7];
    const float* bo   = (const float*)d_in[8];
    const float* W1   = (const float*)d_in[9];
    const float* b1   = (const float*)d_in[10];
    const float* W2   = (const float*)d_in[11];
    const float* b2   = (const float*)d_in[12];
    const float* g1   = (const float*)d_in[13];
    const float* be1  = (const float*)d_in[14];
    const float* g2   = (const float*)d_in[15];
    const float* be2  = (const float*)d_in[16];
    const float* Wout = (const float*)d_in[17];
    const float* bout = (const float*)d_in[18];
    float* out = (float*)d_out;

    char* ws = (char*)d_ws;
    size_t off = 0;
    auto alloc = [&](size_t bytes) -> void* {
        void* p = ws + off;
        off += (bytes + 255) & ~(size_t)255;
        return p;
    };
    bf16_t* Xb   = (bf16_t*)alloc((size_t)NM_ * D_ * 2);          // 16.8 MB
    bf16_t* WT   = (bf16_t*)alloc((size_t)1536 * 512 * 2);        //  1.6 MB
    bf16_t* Qb   = (bf16_t*)alloc((size_t)BH_ * L_ * DH_ * 2);    // 16.8 MB
    bf16_t* Kb   = (bf16_t*)alloc((size_t)BH_ * L_ * DH_ * 2);    // 16.8 MB
    bf16_t* Vb   = (bf16_t*)alloc((size_t)BH_ * L_ * DH_ * 2);    // 16.8 MB
    float*  Mv   = (float*) alloc((size_t)BH_ * L_ * 4);
    float*  kpart= (float*) alloc((size_t)BH_ * 16 * 64 * 4);     // 256 KB
    float*  vpart= (float*) alloc((size_t)BH_ * 16 * 64 * 4);     // 256 KB
    int*    tidx = (int*)   alloc((size_t)BH_ * U_ * 4);
    float*  tout = (float*) alloc((size_t)BH_ * U_ * 64 * 4);
    float*  a2   = (float*) alloc(8 * 512 * 4);
    float*  ffp  = (float*) alloc((size_t)4 * 8 * 2048 * 4);      // 256 KB
    float*  ff2p = (float*) alloc((size_t)8 * 8 * 512 * 4);       // 128 KB
    // attention partials (64*16*40*66 fp32 = 10.8 MB) alias the dead Xb region
    float*  part = (float*)Xb;    // Xb is consumed by k_qkv before k_attn2 runs
    (void)ws_size; (void)in_sizes; (void)n_in; (void)out_size;

    hipLaunchKernelGGL(k_prep,    dim3(4096 + 192), dim3(256), 0, stream, X, Xb, Wq, Wk, Wv, WT);
    hipLaunchKernelGGL(k_qkv,     dim3(12, 128),    dim3(256), 0, stream, Xb, WT, bq, bk, bv, Qb, Kb, Vb, kpart, vpart);
    hipLaunchKernelGGL(k_rowmax,  dim3(8, 64),      dim3(256), 0, stream, Qb, Kb, kpart, Mv);
    hipLaunchKernelGGL(k_topk,    dim3(64),         dim3(64),  0, stream, Mv, tidx);
    hipLaunchKernelGGL(k_attn2,   dim3(NCK_, 64),   dim3(256), 0, stream, Qb, Kb, Vb, tidx, part);
    hipLaunchKernelGGL(k_attnred, dim3(64),         dim3(256), 0, stream, part, tout);
    hipLaunchKernelGGL(k_ctx,     dim3(8),          dim3(256), 0, stream, vpart, tout, Wo, bo, g1, be1, a2);
    hipLaunchKernelGGL(k_ff1p,    dim3(32, 4),      dim3(256), 0, stream, a2, W1, ffp);
    hipLaunchKernelGGL(k_ff2p,    dim3(16, 8),      dim3(256), 0, stream, ffp, b1, W2, ff2p);
    hipLaunchKernelGGL(k_final,   dim3(8),          dim3(256), 0, stream, a2, ff2p, b2, g2, be2, Wout, bout, out);
}